// Round 4
// baseline (4047.432 us; speedup 1.0000x reference)
//
#include <hip/hip_runtime.h>
#include <hip/hip_bf16.h>
#include <math.h>

#define N_NODES 20000
#define N_EDGES 100000
#define N_GRAPHS 200
#define NPG 100
#define EPG 500
#define TOPK 125
#define D_IN 64
#define EMB 300
#define H2 600
#define H4 1200
#define NLAYERS 5
#define NOUT 10

// padded dims
#define NPAD 20096      // 157 * 128
#define EMBP 320
#define H2P 640
#define H4P 1216
#define UVM 2432        // stacked u|v output width (2*1216)
#define TCH_ROWS 5120   // t-chunk rows (40 blocks of 128)

static inline int cdiv(int a, int b) { return (a + b - 1) / b; }

typedef __attribute__((ext_vector_type(8))) short bfrag;
typedef __attribute__((ext_vector_type(4))) float f32x4;

__device__ __forceinline__ ushort f2bf(float f) {
    unsigned u = __builtin_bit_cast(unsigned, f);
    unsigned r = u + 0x7FFFu + ((u >> 16) & 1u);
    return (ushort)(r >> 16);
}
__device__ __forceinline__ float bf2f(ushort h) {
    unsigned u = ((unsigned)h) << 16;
    return __builtin_bit_cast(float, u);
}

template<int NT>
__device__ __forceinline__ void split_planes(float v, ushort& p0, ushort& p1, ushort& p2) {
    p0 = f2bf(v);
    float r = v - bf2f(p0);
    p1 = f2bf(r);
    if (NT == 3) { r -= bf2f(p1); p2 = f2bf(r); } else { p2 = 0; }
}

// async 16B global->LDS copy; LDS dest is wave-uniform base (+ lane*16 by HW)
#define GLOAD_LDS16(gsrc, ldst)                                                   \
    __builtin_amdgcn_global_load_lds(                                             \
        (const __attribute__((address_space(1))) void*)(gsrc),                    \
        (__attribute__((address_space(3))) void*)(ldst), 16, 0, 0)

// ============================================================================
// MFMA GEMM, double-buffered A in LDS, B via register-prefetched global loads.
// C[rows x M] = sum over plane products of A (rows x Kp, bf16 planes) x
// Bt[Mpad x Kp] bf16 planes.  BM=128, BN=64, 4 waves (2x2).
// EPI=0: write fp32 C (+bias, opt relu).  EPI=1: write NT bf16 planes.
// ============================================================================
template<int NT, int RELU, int EPI>
__launch_bounds__(256)
__global__ void mfma_gemm(const ushort* __restrict__ A0, const ushort* __restrict__ A1,
                          const ushort* __restrict__ A2,
                          const ushort* __restrict__ B0, const ushort* __restrict__ B1,
                          const ushort* __restrict__ B2,
                          const float* __restrict__ bias, int Kp, int Mvalid, int ldc,
                          float* __restrict__ Cf, ushort* __restrict__ C0,
                          ushort* __restrict__ C1, ushort* __restrict__ C2) {
    constexpr int BUFSZ = NT * 8192;           // A planes only: 128x32x2B per plane
    __shared__ char smem[2 * BUFSZ];
    const int tid = threadIdx.x;
    const int wave = tid >> 6, lane = tid & 63;
    const int wr = wave >> 1, wc = wave & 1;
    const long rowbase = (long)blockIdx.y * 128;
    const int n0 = blockIdx.x * 64;

    const ushort* Ap[3] = {A0, A1, A2};
    const ushort* Bp[3] = {B0, B1, B2};

    f32x4 acc[4][2] = {};

    // A staging geometry (swizzled global source, linear LDS dest)
    const int arow0 = wave * 16 + (lane >> 2);
    const int aq = lane & 3;

    auto stageA = [&](int buf, int k0) {
#pragma unroll
        for (int p = 0; p < NT; ++p) {
            {
                int r = arow0;
                int q = aq ^ ((r >> 1) & 3);
                GLOAD_LDS16(Ap[p] + (size_t)(rowbase + r) * Kp + k0 + q * 8,
                            smem + buf * BUFSZ + p * 8192 + wave * 1024);
            }
            {
                int r = arow0 + 64;
                int q = aq ^ ((r >> 1) & 3);
                GLOAD_LDS16(Ap[p] + (size_t)(rowbase + r) * Kp + k0 + q * 8,
                            smem + buf * BUFSZ + p * 8192 + 4096 + wave * 1024);
            }
        }
    };

    bfrag bcur[2][3], bnxt[2][3];
    auto loadB = [&](bfrag (&bb)[2][3], int k0) {
#pragma unroll
        for (int n = 0; n < 2; ++n)
#pragma unroll
            for (int p = 0; p < NT; ++p)
                bb[n][p] = *(const bfrag*)(Bp[p] +
                    (size_t)(n0 + wc * 32 + n * 16 + (lane & 15)) * Kp + k0 +
                    (lane >> 4) * 8);
    };

    const int nsteps = Kp >> 5;
    stageA(0, 0);
    loadB(bcur, 0);
    __syncthreads();

    int cur = 0;
    for (int it = 0; it < nsteps; ++it) {
        if (it + 1 < nsteps) {
            stageA(cur ^ 1, (it + 1) << 5);
            loadB(bnxt, (it + 1) << 5);
        }
#pragma unroll
        for (int m = 0; m < 4; ++m) {
            bfrag afr[3];
#pragma unroll
            for (int p = 0; p < NT; ++p) {
                int rA = wr * 64 + m * 16 + (lane & 15);
                int q = (lane >> 4) ^ ((rA >> 1) & 3);
                afr[p] = *(const bfrag*)(smem + cur * BUFSZ + p * 8192 + rA * 64 + q * 16);
            }
#pragma unroll
            for (int n = 0; n < 2; ++n) {
#pragma unroll
                for (int pa = 0; pa < NT; ++pa)
#pragma unroll
                    for (int pb = 0; pb < NT; ++pb)
                        if (pa + pb <= NT - 1)
                            acc[m][n] = __builtin_amdgcn_mfma_f32_16x16x32_bf16(
                                afr[pa], bcur[n][pb], acc[m][n], 0, 0, 0);
            }
        }
        __syncthreads();
        cur ^= 1;
#pragma unroll
        for (int n = 0; n < 2; ++n)
#pragma unroll
            for (int p = 0; p < NT; ++p) bcur[n][p] = bnxt[n][p];
    }

    // ---- epilogue.  C/D layout: col = lane&15, row = (lane>>4)*4 + e
    const int colc = lane & 15, rquad = lane >> 4;
#pragma unroll
    for (int m = 0; m < 4; ++m) {
#pragma unroll
        for (int n = 0; n < 2; ++n) {
            long grow0 = rowbase + wr * 64 + m * 16 + rquad * 4;
            int gcol = n0 + wc * 32 + n * 16 + colc;
            bool cvld = gcol < Mvalid;
            float bv = (bias != nullptr && cvld) ? bias[gcol] : 0.f;
#pragma unroll
            for (int e = 0; e < 4; ++e) {
                float v = acc[m][n][e] + bv;
                if (RELU) v = fmaxf(v, 0.f);
                if (!cvld) v = 0.f;
                size_t o = (size_t)(grow0 + e) * ldc + gcol;
                if (EPI == 0) {
                    Cf[o] = v;
                } else {
                    ushort p0, p1, p2;
                    split_planes<NT>(v, p0, p1, p2);
                    C0[o] = p0; C1[o] = p1;
                    if (NT == 3) C2[o] = p2;
                }
            }
        }
    }
}

// ============================================================================
// conversions
// ============================================================================
template<int NT>
__global__ void conv_w(const float* __restrict__ W, int K, int M, int Kp, int Mp,
                       ushort* __restrict__ P0, ushort* __restrict__ P1,
                       ushort* __restrict__ P2) {
    int idx = blockIdx.x * 256 + threadIdx.x;
    if (idx >= Mp * Kp) return;
    int m = idx / Kp, k = idx % Kp;
    float v = (m < M && k < K) ? W[(size_t)k * M + m] : 0.f;
    ushort p0, p1, p2;
    split_planes<NT>(v, p0, p1, p2);
    P0[idx] = p0; P1[idx] = p1;
    if (NT == 3) P2[idx] = p2;
}

// both layer weights (W1: EMB->H2, W2: H2->EMB) in one dispatch
template<int NT>
__global__ void conv_w2(const float* __restrict__ Wa, const float* __restrict__ Wb,
                        ushort* __restrict__ A0, ushort* __restrict__ A1,
                        ushort* __restrict__ A2, ushort* __restrict__ B0,
                        ushort* __restrict__ B1, ushort* __restrict__ B2) {
    int idx = blockIdx.x * 256 + threadIdx.x;
    const int T1 = H2P * EMBP;   // 204800
    if (idx < T1) {
        int m = idx / EMBP, k = idx % EMBP;
        float v = (m < H2 && k < EMB) ? Wa[(size_t)k * H2 + m] : 0.f;
        ushort p0, p1, p2;
        split_planes<NT>(v, p0, p1, p2);
        A0[idx] = p0; A1[idx] = p1;
        if (NT == 3) A2[idx] = p2;
    } else if (idx < 2 * T1) {
        idx -= T1;
        int m = idx / H2P, k = idx % H2P;
        float v = (m < EMB && k < H2) ? Wb[(size_t)k * EMB + m] : 0.f;
        ushort p0, p1, p2;
        split_planes<NT>(v, p0, p1, p2);
        B0[idx] = p0; B1[idx] = p1;
        if (NT == 3) B2[idx] = p2;
    }
}

template<int NT>
__global__ void conv_a(const float* __restrict__ X, int rows_valid, int ldx, int Kv, int Kp,
                       ushort* __restrict__ P0, ushort* __restrict__ P1,
                       ushort* __restrict__ P2, long total) {
    long idx = (long)blockIdx.x * 256 + threadIdx.x;
    if (idx >= total) return;
    int r = (int)(idx / Kp), k = (int)(idx % Kp);
    float v = (r < rows_valid && k < Kv) ? X[(size_t)r * ldx + k] : 0.f;
    ushort p0, p1, p2;
    split_planes<NT>(v, p0, p1, p2);
    P0[idx] = p0; P1[idx] = p1;
    if (NT == 3) P2[idx] = p2;
}

// ============================================================================
// adjacency build (transposed: At[g][src_local][dst_local] += w)
// ============================================================================
__global__ void build_At(const int* __restrict__ src, const int* __restrict__ dst,
                         const float* __restrict__ w, float* __restrict__ At, int E) {
    int e = blockIdx.x * 256 + threadIdx.x;
    if (e >= E) return;
    int s = src[e], d = dst[e];
    int g = s / NPG;
    atomicAdd(&At[(size_t)g * NPG * NPG + (size_t)(s - g * NPG) * NPG + (d - g * NPG)],
              w ? w[e] : 1.f);
}

// ============================================================================
// fused aggregation: z = At^T h + (1+eps) h, emitted as NT bf16 planes.
// grid = (graph, col-strip of 64, row-half of 50); 4 waves x 13 rows.
// ============================================================================
template<int NT>
__launch_bounds__(256)
__global__ void agg_gemm(const float* __restrict__ h, const float* __restrict__ At,
                         const float* __restrict__ eps, int l,
                         ushort* __restrict__ z0, ushort* __restrict__ z1,
                         ushort* __restrict__ z2) {
    int g = blockIdx.x;
    int strip = blockIdx.y;
    int half = blockIdx.z;
    int lane = threadIdx.x & 63;
    int wave = threadIdx.x >> 6;
    int rb = __builtin_amdgcn_readfirstlane(half * 50 + wave * 13);
    int rcnt = __builtin_amdgcn_readfirstlane(wave == 3 ? 11 : 13);
    const float* Ag = At + (size_t)g * NPG * NPG;
    const float* hg = h + (size_t)g * NPG * EMBP;
    float ep = 1.f + eps[l];

    int c = strip * 64 + lane;
    bool cv = c < EMB;
    float acc[13];
#pragma unroll
    for (int r = 0; r < 13; ++r) acc[r] = 0.f;
#pragma unroll 4
    for (int k = 0; k < NPG; ++k) {
        float hv = cv ? hg[k * EMBP + c] : 0.f;
        const float* ak = Ag + k * NPG + rb;
#pragma unroll
        for (int r = 0; r < 13; ++r)
            if (r < rcnt) acc[r] += ak[r] * hv;
    }
#pragma unroll
    for (int r = 0; r < 13; ++r) {
        if (r < rcnt) {
            int row = g * NPG + rb + r;
            float z = cv ? acc[r] + ep * hg[(rb + r) * EMBP + c] : 0.f;
            ushort p0, p1, p2;
            split_planes<NT>(z, p0, p1, p2);
            size_t o = (size_t)row * EMBP + c;
            z0[o] = p0; z1[o] = p1;
            if (NT == 3) z2[o] = p2;
        }
    }
}

// ============================================================================
// edge score from stacked uv buffer: relu(u[src]+v[dst]+b1) . W2 + b2
// uv row layout: [0:1216) = u, [1216:2432) = v
// ============================================================================
__global__ void edge_score(const float* __restrict__ uv, const float* __restrict__ b1,
                           const float* __restrict__ W2, const float* __restrict__ b2,
                           const int* __restrict__ src, const int* __restrict__ dst,
                           float* __restrict__ score, int E, int node_base) {
    int e = blockIdx.x * 4 + (threadIdx.x >> 6);
    int lane = threadIdx.x & 63;
    if (e >= E) return;
    const float* up = uv + (size_t)(src[e] - node_base) * UVM;
    const float* vp = uv + (size_t)(dst[e] - node_base) * UVM + 1216;
    float acc = 0.f;
    for (int j = lane; j < H4; j += 64) {
        float hj = fmaxf(up[j] + vp[j] + b1[j], 0.f);
        acc += hj * W2[j];
    }
#pragma unroll
    for (int o = 32; o > 0; o >>= 1) acc += __shfl_down(acc, o, 64);
    if (lane == 0) score[e] = acc + b2[0];
}

// ============================================================================
// per-graph top-125 of 500 contiguous edges via bitonic sort
// ============================================================================
__global__ void topk_kernel(const float* __restrict__ score, const int* __restrict__ src,
                            const int* __restrict__ dst, int* __restrict__ c_src,
                            int* __restrict__ c_dst, float* __restrict__ c_w,
                            float* __restrict__ mask) {
    __shared__ float s[512];
    __shared__ short sidx[512];
    int g = blockIdx.x, t = threadIdx.x;
    int base = g * EPG;
    s[t] = (t < EPG) ? score[base + t] : -1e30f;
    sidx[t] = (short)t;
    __syncthreads();
    for (int k = 2; k <= 512; k <<= 1) {
        for (int j = k >> 1; j > 0; j >>= 1) {
            int ixj = t ^ j;
            if (ixj > t) {
                float a = s[t], b = s[ixj];
                bool desc = ((t & k) == 0);
                if (desc ? (a < b) : (a > b)) {
                    s[t] = b; s[ixj] = a;
                    short tmp = sidx[t]; sidx[t] = sidx[ixj]; sidx[ixj] = tmp;
                }
            }
            __syncthreads();
        }
    }
    if (t < TOPK) {
        int e = base + sidx[t];
        int sn = src[e], dn = dst[e];
        c_src[g * TOPK + t] = sn;
        c_dst[g * TOPK + t] = dn;
        c_w[g * TOPK + t] = 1.f / (1.f + expf(-s[t]));
        mask[sn] = 1.f;
        mask[dn] = 1.f;
    }
}

// ============================================================================
// masked mean pool + linear head (h stride EMBP)
// ============================================================================
__global__ void pool_pred(const float* __restrict__ hc, const float* __restrict__ mask,
                          const float* __restrict__ W, const float* __restrict__ b,
                          float* __restrict__ out) {
    int g = blockIdx.x, t = threadIdx.x;
    __shared__ float mloc[NPG];
    __shared__ float pooled[EMB];
    __shared__ float cnt;
    if (t < NPG) mloc[t] = mask[g * NPG + t];
    __syncthreads();
    if (t == 0) {
        float c = 0.f;
        for (int n = 0; n < NPG; ++n) c += mloc[n];
        cnt = fmaxf(c, 1.f);
    }
    __syncthreads();
    for (int c0 = t; c0 < EMB; c0 += 256) {
        float acc = 0.f;
        for (int n = 0; n < NPG; ++n)
            acc += mloc[n] * hc[((size_t)g * NPG + n) * EMBP + c0];
        pooled[c0] = acc / cnt;
    }
    __syncthreads();
    if (t < NOUT) {
        float acc = b[t];
        for (int c0 = 0; c0 < EMB; ++c0) acc += pooled[c0] * W[c0 * NOUT + t];
        out[g * NOUT + t] = acc;
    }
}

// ============================================================================
extern "C" void kernel_launch(void* const* d_in, const int* in_sizes, int n_in,
                              void* d_out, int out_size, void* d_ws, size_t ws_size,
                              hipStream_t stream) {
    const float* x        = (const float*)d_in[0];
    const int*   eidx     = (const int*)d_in[1];
    const float* enc_in_W = (const float*)d_in[4];
    const float* enc_in_b = (const float*)d_in[5];
    const float* enc_W1   = (const float*)d_in[6];
    const float* enc_b1   = (const float*)d_in[7];
    const float* enc_W2   = (const float*)d_in[8];
    const float* enc_b2   = (const float*)d_in[9];
    const float* enc_eps  = (const float*)d_in[10];
    const float* att_W1   = (const float*)d_in[11];
    const float* att_b1   = (const float*)d_in[12];
    const float* att_W2   = (const float*)d_in[13];
    const float* att_b2   = (const float*)d_in[14];
    const float* clf_in_W = (const float*)d_in[15];
    const float* clf_in_b = (const float*)d_in[16];
    const float* clf_W1   = (const float*)d_in[17];
    const float* clf_b1   = (const float*)d_in[18];
    const float* clf_W2   = (const float*)d_in[19];
    const float* clf_b2   = (const float*)d_in[20];
    const float* clf_eps  = (const float*)d_in[21];
    const float* pred_W   = (const float*)d_in[22];
    const float* pred_b   = (const float*)d_in[23];
    float* out = (float*)d_out;

    const int* src = eidx;
    const int* dst = eidx + N_EDGES;

    // ---------------- workspace layout (bytes) ----------------
    char* ws = (char*)d_ws;
    constexpr size_t SZ_H    = (size_t)NPAD * EMBP * 4;        // 25,722,880
    constexpr size_t SZ_ZP   = (size_t)NPAD * EMBP * 2;        // 12,861,440 per plane
    constexpr size_t SZ_TP   = (size_t)TCH_ROWS * H2P * 2;     //  6,553,600 per plane
    constexpr size_t SZ_WSP  = (size_t)H2P * EMBP * 2;         //    409,600 per plane
    constexpr size_t SZ_WUVP = (size_t)UVM * EMBP * 2;         //  1,556,480 per plane

    constexpr size_t OFF_H   = 0;
    constexpr size_t OFF_Z   = OFF_H + SZ_H;
    constexpr size_t OFF_T   = OFF_Z + 3 * SZ_ZP;              //  64,307,200
    constexpr size_t OFF_WSL = OFF_T + 3 * SZ_TP;              //  83,968,000
    constexpr size_t OFF_AT  = OFF_WSL + 6 * SZ_WSP;           //  86,425,600
    constexpr size_t OFF_SC  = OFF_AT + (size_t)N_GRAPHS * NPG * NPG * 4;  // 102,425,600
    constexpr size_t OFF_CW  = OFF_SC + (size_t)N_EDGES * 4;
    constexpr size_t OFF_MK  = OFF_CW + (size_t)N_GRAPHS * TOPK * 4;
    constexpr size_t OFF_CS  = OFF_MK + (size_t)N_NODES * 4;
    constexpr size_t OFF_CD  = OFF_CS + (size_t)N_GRAPHS * TOPK * 4;
    // high-water: OFF_CD + 100000 = 103,205,600 (same as round 3)

    float*  h   = (float*)(ws + OFF_H);
    ushort* z0  = (ushort*)(ws + OFF_Z);
    ushort* z1  = (ushort*)(ws + OFF_Z + SZ_ZP);
    ushort* z2  = (ushort*)(ws + OFF_Z + 2 * SZ_ZP);
    ushort* t0  = (ushort*)(ws + OFF_T);
    ushort* t1  = (ushort*)(ws + OFF_T + SZ_TP);
    ushort* t2  = (ushort*)(ws + OFF_T + 2 * SZ_TP);
    ushort* w0p[3] = {(ushort*)(ws + OFF_WSL), (ushort*)(ws + OFF_WSL + SZ_WSP),
                      (ushort*)(ws + OFF_WSL + 2 * SZ_WSP)};
    ushort* w1p[3] = {(ushort*)(ws + OFF_WSL + 3 * SZ_WSP), (ushort*)(ws + OFF_WSL + 4 * SZ_WSP),
                      (ushort*)(ws + OFF_WSL + 5 * SZ_WSP)};
    float*  At    = (float*)(ws + OFF_AT);
    float*  score = (float*)(ws + OFF_SC);
    float*  c_w   = (float*)(ws + OFF_CW);
    float*  mask  = (float*)(ws + OFF_MK);
    int*    c_src = (int*)(ws + OFF_CS);
    int*    c_dst = (int*)(ws + OFF_CD);

    // overlays
    ushort* xp[3] = {z0, z1, z2};              // x planes live in z region pre-layers
    // scores phase (encoder At + t/wsl regions dead by then):
    float*  uvbuf = (float*)(ws + OFF_T);      // 2560 x 2432 x 4 = 24,903,680 B (T..into At)
    constexpr size_t OFF_WUV = OFF_T + 24903680;               // 89,210,880 (inside At region)
    ushort* wuvp[3] = {(ushort*)(ws + OFF_WUV), (ushort*)(ws + OFF_WUV + SZ_WUVP),
                       (ushort*)(ws + OFF_WUV + 2 * SZ_WUVP)}; // ends 93,880,320 < 102,425,600

    const int chunk_start[4] = {0, 40, 80, 120};   // in 128-row blocks
    const int chunk_nb[4]    = {40, 40, 40, 37};

    // ================= Phase E: encoder (NT=3) =================
    conv_w<3><<<(EMBP * 64) / 256, 256, 0, stream>>>(enc_in_W, D_IN, EMB, 64, EMBP,
                                                     w0p[0], w0p[1], w0p[2]);
    conv_a<3><<<(int)(((long)NPAD * 64) / 256), 256, 0, stream>>>(
        x, N_NODES, D_IN, D_IN, 64, xp[0], xp[1], xp[2], (long)NPAD * 64);
    mfma_gemm<3, 0, 0><<<dim3(EMBP / 64, NPAD / 128), 256, 0, stream>>>(
        xp[0], xp[1], xp[2], w0p[0], w0p[1], w0p[2], enc_in_b, 64, EMB, EMBP,
        h, nullptr, nullptr, nullptr);

    hipMemsetAsync(At, 0, (size_t)N_GRAPHS * NPG * NPG * 4, stream);
    build_At<<<cdiv(N_EDGES, 256), 256, 0, stream>>>(src, dst, nullptr, At, N_EDGES);

    for (int l = 0; l < NLAYERS; ++l) {
        agg_gemm<3><<<dim3(N_GRAPHS, 5, 2), 256, 0, stream>>>(h, At, enc_eps, l, z0, z1, z2);
        conv_w2<3><<<(2 * H2P * EMBP) / 256, 256, 0, stream>>>(
            enc_W1 + (size_t)l * EMB * H2, enc_W2 + (size_t)l * H2 * EMB,
            w0p[0], w0p[1], w0p[2], w1p[0], w1p[1], w1p[2]);
        for (int c = 0; c < 4; ++c) {
            size_t r0 = (size_t)chunk_start[c] * 128;
            int nb = chunk_nb[c];
            mfma_gemm<3, 1, 1><<<dim3(H2P / 64, nb), 256, 0, stream>>>(
                z0 + r0 * EMBP, z1 + r0 * EMBP, z2 + r0 * EMBP,
                w0p[0], w0p[1], w0p[2], enc_b1 + l * H2, EMBP, H2, H2P,
                nullptr, t0, t1, t2);
            if (l < NLAYERS - 1)
                mfma_gemm<3, 1, 0><<<dim3(EMBP / 64, nb), 256, 0, stream>>>(
                    t0, t1, t2, w1p[0], w1p[1], w1p[2], enc_b2 + l * EMB, H2P, EMB, EMBP,
                    h + r0 * EMBP, nullptr, nullptr, nullptr);
            else   // final layer: emit bf16 planes (no relu) straight into z region (= hp)
                mfma_gemm<3, 0, 1><<<dim3(EMBP / 64, nb), 256, 0, stream>>>(
                    t0, t1, t2, w1p[0], w1p[1], w1p[2], enc_b2 + l * EMB, H2P, EMB, EMBP,
                    nullptr, z0 + r0 * EMBP, z1 + r0 * EMBP, z2 + r0 * EMBP);
        }
    }

    // ================= Phase S: edge scores + topk =================
    // stacked Wu|Wv planes (bias folded into edge_score)
    conv_w<3><<<cdiv(1216 * EMBP, 256), 256, 0, stream>>>(
        att_W1, EMB, H4, EMBP, 1216, wuvp[0], wuvp[1], wuvp[2]);
    conv_w<3><<<cdiv(1216 * EMBP, 256), 256, 0, stream>>>(
        att_W1 + (size_t)EMB * H4, EMB, H4, EMBP, 1216,
        wuvp[0] + (size_t)1216 * EMBP, wuvp[1] + (size_t)1216 * EMBP,
        wuvp[2] + (size_t)1216 * EMBP);
    for (int sc = 0; sc < 8; ++sc) {
        size_t nb0 = (size_t)sc * 2500;
        mfma_gemm<3, 0, 0><<<dim3(UVM / 64, 20), 256, 0, stream>>>(
            z0 + nb0 * EMBP, z1 + nb0 * EMBP, z2 + nb0 * EMBP,
            wuvp[0], wuvp[1], wuvp[2], nullptr, EMBP, UVM, UVM,
            uvbuf, nullptr, nullptr, nullptr);
        edge_score<<<cdiv(12500, 4), 256, 0, stream>>>(
            uvbuf, att_b1, att_W2, att_b2, src + sc * 12500, dst + sc * 12500,
            score + sc * 12500, 12500, (int)nb0);
    }
    hipMemsetAsync(mask, 0, N_NODES * 4, stream);
    topk_kernel<<<N_GRAPHS, 512, 0, stream>>>(score, src, dst, c_src, c_dst, c_w, mask);

    // ================= Phase C: classifier (NT=2) =================
    conv_w<2><<<(EMBP * 64) / 256, 256, 0, stream>>>(clf_in_W, D_IN, EMB, 64, EMBP,
                                                     w0p[0], w0p[1], w0p[2]);
    conv_a<2><<<(int)(((long)NPAD * 64) / 256), 256, 0, stream>>>(
        x, N_NODES, D_IN, D_IN, 64, xp[0], xp[1], xp[2], (long)NPAD * 64);
    mfma_gemm<2, 0, 0><<<dim3(EMBP / 64, NPAD / 128), 256, 0, stream>>>(
        xp[0], xp[1], nullptr, w0p[0], w0p[1], nullptr, clf_in_b, 64, EMB, EMBP,
        h, nullptr, nullptr, nullptr);

    hipMemsetAsync(At, 0, (size_t)N_GRAPHS * NPG * NPG * 4, stream);
    build_At<<<cdiv(N_GRAPHS * TOPK, 256), 256, 0, stream>>>(c_src, c_dst, c_w, At,
                                                             N_GRAPHS * TOPK);

    for (int l = 0; l < NLAYERS; ++l) {
        agg_gemm<2><<<dim3(N_GRAPHS, 5, 2), 256, 0, stream>>>(h, At, clf_eps, l,
                                                              z0, z1, nullptr);
        conv_w2<2><<<(2 * H2P * EMBP) / 256, 256, 0, stream>>>(
            clf_W1 + (size_t)l * EMB * H2, clf_W2 + (size_t)l * H2 * EMB,
            w0p[0], w0p[1], nullptr, w1p[0], w1p[1], nullptr);
        for (int c = 0; c < 4; ++c) {
            size_t r0 = (size_t)chunk_start[c] * 128;
            int nb = chunk_nb[c];
            mfma_gemm<2, 1, 1><<<dim3(H2P / 64, nb), 256, 0, stream>>>(
                z0 + r0 * EMBP, z1 + r0 * EMBP, nullptr,
                w0p[0], w0p[1], nullptr, clf_b1 + l * H2, EMBP, H2, H2P,
                nullptr, t0, t1, nullptr);
            if (l < NLAYERS - 1)
                mfma_gemm<2, 1, 0><<<dim3(EMBP / 64, nb), 256, 0, stream>>>(
                    t0, t1, nullptr, w1p[0], w1p[1], nullptr, clf_b2 + l * EMB, H2P, EMB, EMBP,
                    h + r0 * EMBP, nullptr, nullptr, nullptr);
            else
                mfma_gemm<2, 0, 0><<<dim3(EMBP / 64, nb), 256, 0, stream>>>(
                    t0, t1, nullptr, w1p[0], w1p[1], nullptr, clf_b2 + l * EMB, H2P, EMB, EMBP,
                    h + r0 * EMBP, nullptr, nullptr, nullptr);
        }
    }

    // ================= pool + head =================
    pool_pred<<<N_GRAPHS, 256, 0, stream>>>(h, mask, pred_W, pred_b, out);
}

// Round 5
// 2998.740 us; speedup vs baseline: 1.3497x; 1.3497x over previous
//
#include <hip/hip_runtime.h>
#include <hip/hip_bf16.h>
#include <math.h>

#define N_NODES 20000
#define N_EDGES 100000
#define N_GRAPHS 200
#define NPG 100
#define EPG 500
#define TOPK 125
#define D_IN 64
#define EMB 300
#define H2 600
#define H4 1200
#define NLAYERS 5
#define NOUT 10

// padded dims
#define NPAD 20096      // 157 * 128
#define EMBP 320
#define H2P 640
#define H4P 1216
#define UVM 2432        // stacked u|v output width (2*1216)
#define TCH_ROWS 5120   // t-chunk rows (40 blocks of 128)

static inline int cdiv(int a, int b) { return (a + b - 1) / b; }

typedef __attribute__((ext_vector_type(8))) short bfrag;
typedef __attribute__((ext_vector_type(4))) float f32x4;

__device__ __forceinline__ ushort f2bf(float f) {
    unsigned u = __builtin_bit_cast(unsigned, f);
    unsigned r = u + 0x7FFFu + ((u >> 16) & 1u);
    return (ushort)(r >> 16);
}
__device__ __forceinline__ float bf2f(ushort h) {
    unsigned u = ((unsigned)h) << 16;
    return __builtin_bit_cast(float, u);
}

template<int NT>
__device__ __forceinline__ void split_planes(float v, ushort& p0, ushort& p1, ushort& p2) {
    p0 = f2bf(v);
    float r = v - bf2f(p0);
    p1 = f2bf(r);
    if (NT == 3) { r -= bf2f(p1); p2 = f2bf(r); } else { p2 = 0; }
}

// async 16B global->LDS copy; LDS dest is wave-uniform base (+ lane*16 by HW)
#define GLOAD_LDS16(gsrc, ldst)                                                   \
    __builtin_amdgcn_global_load_lds(                                             \
        (const __attribute__((address_space(1))) void*)(gsrc),                    \
        (__attribute__((address_space(3))) void*)(ldst), 16, 0, 0)

// ============================================================================
// MFMA GEMM (round-3 proven structure): A and B staged via global_load_lds,
// 2 barriers per K-step.  C[rows x M] = sum over plane products of
// A (rows x Kp, bf16 planes) x Bt[Mpad x Kp] bf16 planes.
// BM=128, BN=64, 4 waves (2x2).
// EPI=0: write fp32 C (+bias, opt relu).  EPI=1: write NT bf16 planes.
// ============================================================================
template<int NT, int RELU, int EPI>
__launch_bounds__(256)
__global__ void mfma_gemm(const ushort* __restrict__ A0, const ushort* __restrict__ A1,
                          const ushort* __restrict__ A2,
                          const ushort* __restrict__ B0, const ushort* __restrict__ B1,
                          const ushort* __restrict__ B2,
                          const float* __restrict__ bias, int Kp, int Mvalid, int ldc,
                          float* __restrict__ Cf, ushort* __restrict__ C0,
                          ushort* __restrict__ C1, ushort* __restrict__ C2) {
    __shared__ char smem[NT * 8192 + NT * 4096];   // A planes (128x32x2B) + B planes (64x32x2B)
    const int tid = threadIdx.x;
    const int wave = tid >> 6, lane = tid & 63;
    const int wr = wave >> 1, wc = wave & 1;
    const long rowbase = (long)blockIdx.y * 128;
    const int n0 = blockIdx.x * 64;

    const ushort* Ap[3] = {A0, A1, A2};
    const ushort* Bp[3] = {B0, B1, B2};

    f32x4 acc[4][2] = {};

    // staging geometry (swizzled global source, linear LDS dest)
    const int arow0 = wave * 16 + (lane >> 2);         // A it=0 row; it=1 adds 64
    const int aq = lane & 3;
    const int brow = wave * 16 + (lane >> 2);          // B row (0..63)

    for (int k0 = 0; k0 < Kp; k0 += 32) {
        // ---- stage A planes (2 iters of 4KB) and B planes (1 iter of 4KB)
#pragma unroll
        for (int p = 0; p < NT; ++p) {
            {
                int r = arow0;
                int q = aq ^ ((r >> 1) & 3);
                const ushort* g = Ap[p] + (size_t)(rowbase + r) * Kp + k0 + q * 8;
                GLOAD_LDS16(g, smem + p * 8192 + wave * 1024);
            }
            {
                int r = arow0 + 64;
                int q = aq ^ ((r >> 1) & 3);
                const ushort* g = Ap[p] + (size_t)(rowbase + r) * Kp + k0 + q * 8;
                GLOAD_LDS16(g, smem + p * 8192 + 4096 + wave * 1024);
            }
            {
                int q = aq ^ ((brow >> 1) & 3);
                const ushort* g = Bp[p] + (size_t)(n0 + brow) * Kp + k0 + q * 8;
                GLOAD_LDS16(g, smem + NT * 8192 + p * 4096 + wave * 1024);
            }
        }
        __syncthreads();

        // ---- fragments + MFMA
        bfrag bfr[2][3];
#pragma unroll
        for (int n = 0; n < 2; ++n)
#pragma unroll
            for (int p = 0; p < NT; ++p) {
                int rB = wc * 32 + n * 16 + (lane & 15);
                int q = (lane >> 4) ^ ((rB >> 1) & 3);
                bfr[n][p] = *(const bfrag*)(smem + NT * 8192 + p * 4096 + rB * 64 + q * 16);
            }
#pragma unroll
        for (int m = 0; m < 4; ++m) {
            bfrag afr[3];
#pragma unroll
            for (int p = 0; p < NT; ++p) {
                int rA = wr * 64 + m * 16 + (lane & 15);
                int q = (lane >> 4) ^ ((rA >> 1) & 3);
                afr[p] = *(const bfrag*)(smem + p * 8192 + rA * 64 + q * 16);
            }
#pragma unroll
            for (int n = 0; n < 2; ++n) {
#pragma unroll
                for (int pa = 0; pa < NT; ++pa)
#pragma unroll
                    for (int pb = 0; pb < NT; ++pb)
                        if (pa + pb <= NT - 1)
                            acc[m][n] = __builtin_amdgcn_mfma_f32_16x16x32_bf16(
                                afr[pa], bfr[n][pb], acc[m][n], 0, 0, 0);
            }
        }
        __syncthreads();
    }

    // ---- epilogue.  C/D layout: col = lane&15, row = (lane>>4)*4 + e
    const int colc = lane & 15, rquad = lane >> 4;
#pragma unroll
    for (int m = 0; m < 4; ++m) {
#pragma unroll
        for (int n = 0; n < 2; ++n) {
            long grow0 = rowbase + wr * 64 + m * 16 + rquad * 4;
            int gcol = n0 + wc * 32 + n * 16 + colc;
            bool cvld = gcol < Mvalid;
            float bv = (bias != nullptr && cvld) ? bias[gcol] : 0.f;
#pragma unroll
            for (int e = 0; e < 4; ++e) {
                float v = acc[m][n][e] + bv;
                if (RELU) v = fmaxf(v, 0.f);
                if (!cvld) v = 0.f;
                size_t o = (size_t)(grow0 + e) * ldc + gcol;
                if (EPI == 0) {
                    Cf[o] = v;
                } else {
                    ushort p0, p1, p2;
                    split_planes<NT>(v, p0, p1, p2);
                    C0[o] = p0; C1[o] = p1;
                    if (NT == 3) C2[o] = p2;
                }
            }
        }
    }
}

// ============================================================================
// conversions
// ============================================================================
template<int NT>
__global__ void conv_w(const float* __restrict__ W, int K, int M, int Kp, int Mp,
                       ushort* __restrict__ P0, ushort* __restrict__ P1,
                       ushort* __restrict__ P2) {
    int idx = blockIdx.x * 256 + threadIdx.x;
    if (idx >= Mp * Kp) return;
    int m = idx / Kp, k = idx % Kp;
    float v = (m < M && k < K) ? W[(size_t)k * M + m] : 0.f;
    ushort p0, p1, p2;
    split_planes<NT>(v, p0, p1, p2);
    P0[idx] = p0; P1[idx] = p1;
    if (NT == 3) P2[idx] = p2;
}

// both layer weights (W1: EMB->H2, W2: H2->EMB) in one dispatch
template<int NT>
__global__ void conv_w2(const float* __restrict__ Wa, const float* __restrict__ Wb,
                        ushort* __restrict__ A0, ushort* __restrict__ A1,
                        ushort* __restrict__ A2, ushort* __restrict__ B0,
                        ushort* __restrict__ B1, ushort* __restrict__ B2) {
    int idx = blockIdx.x * 256 + threadIdx.x;
    const int T1 = H2P * EMBP;   // 204800
    if (idx < T1) {
        int m = idx / EMBP, k = idx % EMBP;
        float v = (m < H2 && k < EMB) ? Wa[(size_t)k * H2 + m] : 0.f;
        ushort p0, p1, p2;
        split_planes<NT>(v, p0, p1, p2);
        A0[idx] = p0; A1[idx] = p1;
        if (NT == 3) A2[idx] = p2;
    } else if (idx < 2 * T1) {
        idx -= T1;
        int m = idx / H2P, k = idx % H2P;
        float v = (m < EMB && k < H2) ? Wb[(size_t)k * EMB + m] : 0.f;
        ushort p0, p1, p2;
        split_planes<NT>(v, p0, p1, p2);
        B0[idx] = p0; B1[idx] = p1;
        if (NT == 3) B2[idx] = p2;
    }
}

template<int NT>
__global__ void conv_a(const float* __restrict__ X, int rows_valid, int ldx, int Kv, int Kp,
                       ushort* __restrict__ P0, ushort* __restrict__ P1,
                       ushort* __restrict__ P2, long total) {
    long idx = (long)blockIdx.x * 256 + threadIdx.x;
    if (idx >= total) return;
    int r = (int)(idx / Kp), k = (int)(idx % Kp);
    float v = (r < rows_valid && k < Kv) ? X[(size_t)r * ldx + k] : 0.f;
    ushort p0, p1, p2;
    split_planes<NT>(v, p0, p1, p2);
    P0[idx] = p0; P1[idx] = p1;
    if (NT == 3) P2[idx] = p2;
}

// ============================================================================
// adjacency build (transposed: At[g][src_local][dst_local] += w)
// ============================================================================
__global__ void build_At(const int* __restrict__ src, const int* __restrict__ dst,
                         const float* __restrict__ w, float* __restrict__ At, int E) {
    int e = blockIdx.x * 256 + threadIdx.x;
    if (e >= E) return;
    int s = src[e], d = dst[e];
    int g = s / NPG;
    atomicAdd(&At[(size_t)g * NPG * NPG + (size_t)(s - g * NPG) * NPG + (d - g * NPG)],
              w ? w[e] : 1.f);
}

// ============================================================================
// fused aggregation (round-3 proven): z = At^T h + (1+eps) h, NT bf16 planes.
// grid = (graph, col-strip of 64); block = 4 waves x 25 rows each.
// ============================================================================
template<int NT>
__launch_bounds__(256)
__global__ void agg_gemm(const float* __restrict__ h, const float* __restrict__ At,
                         const float* __restrict__ eps, int l,
                         ushort* __restrict__ z0, ushort* __restrict__ z1,
                         ushort* __restrict__ z2) {
    int g = blockIdx.x;
    int strip = blockIdx.y;
    int lane = threadIdx.x & 63;
    int rb = __builtin_amdgcn_readfirstlane((threadIdx.x >> 6) * 25);
    const float* Ag = At + (size_t)g * NPG * NPG;
    const float* hg = h + (size_t)g * NPG * EMBP;
    float ep = 1.f + eps[l];

    int c = strip * 64 + lane;
    bool cv = c < EMB;
    float acc[25];
#pragma unroll
    for (int r = 0; r < 25; ++r) acc[r] = 0.f;
#pragma unroll 4
    for (int k = 0; k < NPG; ++k) {
        float hv = cv ? hg[k * EMBP + c] : 0.f;
        const float* ak = Ag + k * NPG + rb;
#pragma unroll
        for (int r = 0; r < 25; ++r) acc[r] += ak[r] * hv;
    }
#pragma unroll
    for (int r = 0; r < 25; ++r) {
        int row = g * NPG + rb + r;
        float z = cv ? acc[r] + ep * hg[(rb + r) * EMBP + c] : 0.f;
        ushort p0, p1, p2;
        split_planes<NT>(z, p0, p1, p2);
        size_t o = (size_t)row * EMBP + c;
        z0[o] = p0; z1[o] = p1;
        if (NT == 3) z2[o] = p2;
    }
}

// ============================================================================
// edge score from stacked uv buffer: relu(u[src]+v[dst]+b1) . W2 + b2
// uv row layout: [0:1216) = u, [1216:2432) = v
// ============================================================================
__global__ void edge_score(const float* __restrict__ uv, const float* __restrict__ b1,
                           const float* __restrict__ W2, const float* __restrict__ b2,
                           const int* __restrict__ src, const int* __restrict__ dst,
                           float* __restrict__ score, int E, int node_base) {
    int e = blockIdx.x * 4 + (threadIdx.x >> 6);
    int lane = threadIdx.x & 63;
    if (e >= E) return;
    const float* up = uv + (size_t)(src[e] - node_base) * UVM;
    const float* vp = uv + (size_t)(dst[e] - node_base) * UVM + 1216;
    float acc = 0.f;
    for (int j = lane; j < H4; j += 64) {
        float hj = fmaxf(up[j] + vp[j] + b1[j], 0.f);
        acc += hj * W2[j];
    }
#pragma unroll
    for (int o = 32; o > 0; o >>= 1) acc += __shfl_down(acc, o, 64);
    if (lane == 0) score[e] = acc + b2[0];
}

// ============================================================================
// per-graph top-125 of 500 contiguous edges via bitonic sort
// ============================================================================
__global__ void topk_kernel(const float* __restrict__ score, const int* __restrict__ src,
                            const int* __restrict__ dst, int* __restrict__ c_src,
                            int* __restrict__ c_dst, float* __restrict__ c_w,
                            float* __restrict__ mask) {
    __shared__ float s[512];
    __shared__ short sidx[512];
    int g = blockIdx.x, t = threadIdx.x;
    int base = g * EPG;
    s[t] = (t < EPG) ? score[base + t] : -1e30f;
    sidx[t] = (short)t;
    __syncthreads();
    for (int k = 2; k <= 512; k <<= 1) {
        for (int j = k >> 1; j > 0; j >>= 1) {
            int ixj = t ^ j;
            if (ixj > t) {
                float a = s[t], b = s[ixj];
                bool desc = ((t & k) == 0);
                if (desc ? (a < b) : (a > b)) {
                    s[t] = b; s[ixj] = a;
                    short tmp = sidx[t]; sidx[t] = sidx[ixj]; sidx[ixj] = tmp;
                }
            }
            __syncthreads();
        }
    }
    if (t < TOPK) {
        int e = base + sidx[t];
        int sn = src[e], dn = dst[e];
        c_src[g * TOPK + t] = sn;
        c_dst[g * TOPK + t] = dn;
        c_w[g * TOPK + t] = 1.f / (1.f + expf(-s[t]));
        mask[sn] = 1.f;
        mask[dn] = 1.f;
    }
}

// ============================================================================
// masked mean pool + linear head (h stride EMBP)
// ============================================================================
__global__ void pool_pred(const float* __restrict__ hc, const float* __restrict__ mask,
                          const float* __restrict__ W, const float* __restrict__ b,
                          float* __restrict__ out) {
    int g = blockIdx.x, t = threadIdx.x;
    __shared__ float mloc[NPG];
    __shared__ float pooled[EMB];
    __shared__ float cnt;
    if (t < NPG) mloc[t] = mask[g * NPG + t];
    __syncthreads();
    if (t == 0) {
        float c = 0.f;
        for (int n = 0; n < NPG; ++n) c += mloc[n];
        cnt = fmaxf(c, 1.f);
    }
    __syncthreads();
    for (int c0 = t; c0 < EMB; c0 += 256) {
        float acc = 0.f;
        for (int n = 0; n < NPG; ++n)
            acc += mloc[n] * hc[((size_t)g * NPG + n) * EMBP + c0];
        pooled[c0] = acc / cnt;
    }
    __syncthreads();
    if (t < NOUT) {
        float acc = b[t];
        for (int c0 = 0; c0 < EMB; ++c0) acc += pooled[c0] * W[c0 * NOUT + t];
        out[g * NOUT + t] = acc;
    }
}

// ============================================================================
extern "C" void kernel_launch(void* const* d_in, const int* in_sizes, int n_in,
                              void* d_out, int out_size, void* d_ws, size_t ws_size,
                              hipStream_t stream) {
    const float* x        = (const float*)d_in[0];
    const int*   eidx     = (const int*)d_in[1];
    const float* enc_in_W = (const float*)d_in[4];
    const float* enc_in_b = (const float*)d_in[5];
    const float* enc_W1   = (const float*)d_in[6];
    const float* enc_b1   = (const float*)d_in[7];
    const float* enc_W2   = (const float*)d_in[8];
    const float* enc_b2   = (const float*)d_in[9];
    const float* enc_eps  = (const float*)d_in[10];
    const float* att_W1   = (const float*)d_in[11];
    const float* att_b1   = (const float*)d_in[12];
    const float* att_W2   = (const float*)d_in[13];
    const float* att_b2   = (const float*)d_in[14];
    const float* clf_in_W = (const float*)d_in[15];
    const float* clf_in_b = (const float*)d_in[16];
    const float* clf_W1   = (const float*)d_in[17];
    const float* clf_b1   = (const float*)d_in[18];
    const float* clf_W2   = (const float*)d_in[19];
    const float* clf_b2   = (const float*)d_in[20];
    const float* clf_eps  = (const float*)d_in[21];
    const float* pred_W   = (const float*)d_in[22];
    const float* pred_b   = (const float*)d_in[23];
    float* out = (float*)d_out;

    const int* src = eidx;
    const int* dst = eidx + N_EDGES;

    // ---------------- workspace layout (bytes) ----------------
    char* ws = (char*)d_ws;
    constexpr size_t SZ_H    = (size_t)NPAD * EMBP * 4;        // 25,722,880
    constexpr size_t SZ_ZP   = (size_t)NPAD * EMBP * 2;        // 12,861,440 per plane
    constexpr size_t SZ_TP   = (size_t)TCH_ROWS * H2P * 2;     //  6,553,600 per plane
    constexpr size_t SZ_WSP  = (size_t)H2P * EMBP * 2;         //    409,600 per plane
    constexpr size_t SZ_WUVP = (size_t)UVM * EMBP * 2;         //  1,556,480 per plane

    constexpr size_t OFF_H   = 0;
    constexpr size_t OFF_Z   = OFF_H + SZ_H;
    constexpr size_t OFF_T   = OFF_Z + 3 * SZ_ZP;              //  64,307,200
    constexpr size_t OFF_WSL = OFF_T + 3 * SZ_TP;              //  83,968,000
    constexpr size_t OFF_AT  = OFF_WSL + 6 * SZ_WSP;           //  86,425,600
    constexpr size_t OFF_SC  = OFF_AT + (size_t)N_GRAPHS * NPG * NPG * 4;  // 102,425,600
    constexpr size_t OFF_CW  = OFF_SC + (size_t)N_EDGES * 4;
    constexpr size_t OFF_MK  = OFF_CW + (size_t)N_GRAPHS * TOPK * 4;
    constexpr size_t OFF_CS  = OFF_MK + (size_t)N_NODES * 4;
    constexpr size_t OFF_CD  = OFF_CS + (size_t)N_GRAPHS * TOPK * 4;
    // high-water: OFF_CD + 100000 = 103,205,600 (same as rounds 3/4)

    float*  h   = (float*)(ws + OFF_H);
    ushort* z0  = (ushort*)(ws + OFF_Z);
    ushort* z1  = (ushort*)(ws + OFF_Z + SZ_ZP);
    ushort* z2  = (ushort*)(ws + OFF_Z + 2 * SZ_ZP);
    ushort* t0  = (ushort*)(ws + OFF_T);
    ushort* t1  = (ushort*)(ws + OFF_T + SZ_TP);
    ushort* t2  = (ushort*)(ws + OFF_T + 2 * SZ_TP);
    ushort* w0p[3] = {(ushort*)(ws + OFF_WSL), (ushort*)(ws + OFF_WSL + SZ_WSP),
                      (ushort*)(ws + OFF_WSL + 2 * SZ_WSP)};
    ushort* w1p[3] = {(ushort*)(ws + OFF_WSL + 3 * SZ_WSP), (ushort*)(ws + OFF_WSL + 4 * SZ_WSP),
                      (ushort*)(ws + OFF_WSL + 5 * SZ_WSP)};
    float*  At    = (float*)(ws + OFF_AT);
    float*  score = (float*)(ws + OFF_SC);
    float*  c_w   = (float*)(ws + OFF_CW);
    float*  mask  = (float*)(ws + OFF_MK);
    int*    c_src = (int*)(ws + OFF_CS);
    int*    c_dst = (int*)(ws + OFF_CD);

    // overlays
    ushort* xp[3] = {z0, z1, z2};              // x planes live in z region pre-layers
    // scores phase (encoder At + t/wsl regions dead by then):
    float*  uvbuf = (float*)(ws + OFF_T);      // 2560 x 2432 x 4 = 24,903,680 B (T..into At)
    constexpr size_t OFF_WUV = OFF_T + 24903680;               // 89,210,880 (inside At region)
    ushort* wuvp[3] = {(ushort*)(ws + OFF_WUV), (ushort*)(ws + OFF_WUV + SZ_WUVP),
                       (ushort*)(ws + OFF_WUV + 2 * SZ_WUVP)}; // ends 93,880,320 < 102,425,600

    const int chunk_start[4] = {0, 40, 80, 120};   // in 128-row blocks
    const int chunk_nb[4]    = {40, 40, 40, 37};

    // ================= Phase E: encoder (NT=3) =================
    conv_w<3><<<(EMBP * 64) / 256, 256, 0, stream>>>(enc_in_W, D_IN, EMB, 64, EMBP,
                                                     w0p[0], w0p[1], w0p[2]);
    conv_a<3><<<(int)(((long)NPAD * 64) / 256), 256, 0, stream>>>(
        x, N_NODES, D_IN, D_IN, 64, xp[0], xp[1], xp[2], (long)NPAD * 64);
    mfma_gemm<3, 0, 0><<<dim3(EMBP / 64, NPAD / 128), 256, 0, stream>>>(
        xp[0], xp[1], xp[2], w0p[0], w0p[1], w0p[2], enc_in_b, 64, EMB, EMBP,
        h, nullptr, nullptr, nullptr);

    hipMemsetAsync(At, 0, (size_t)N_GRAPHS * NPG * NPG * 4, stream);
    build_At<<<cdiv(N_EDGES, 256), 256, 0, stream>>>(src, dst, nullptr, At, N_EDGES);

    for (int l = 0; l < NLAYERS; ++l) {
        agg_gemm<3><<<dim3(N_GRAPHS, 5), 256, 0, stream>>>(h, At, enc_eps, l, z0, z1, z2);
        conv_w2<3><<<(2 * H2P * EMBP) / 256, 256, 0, stream>>>(
            enc_W1 + (size_t)l * EMB * H2, enc_W2 + (size_t)l * H2 * EMB,
            w0p[0], w0p[1], w0p[2], w1p[0], w1p[1], w1p[2]);
        for (int c = 0; c < 4; ++c) {
            size_t r0 = (size_t)chunk_start[c] * 128;
            int nb = chunk_nb[c];
            mfma_gemm<3, 1, 1><<<dim3(H2P / 64, nb), 256, 0, stream>>>(
                z0 + r0 * EMBP, z1 + r0 * EMBP, z2 + r0 * EMBP,
                w0p[0], w0p[1], w0p[2], enc_b1 + l * H2, EMBP, H2, H2P,
                nullptr, t0, t1, t2);
            if (l < NLAYERS - 1)
                mfma_gemm<3, 1, 0><<<dim3(EMBP / 64, nb), 256, 0, stream>>>(
                    t0, t1, t2, w1p[0], w1p[1], w1p[2], enc_b2 + l * EMB, H2P, EMB, EMBP,
                    h + r0 * EMBP, nullptr, nullptr, nullptr);
            else   // final layer: emit bf16 planes (no relu) straight into z region
                mfma_gemm<3, 0, 1><<<dim3(EMBP / 64, nb), 256, 0, stream>>>(
                    t0, t1, t2, w1p[0], w1p[1], w1p[2], enc_b2 + l * EMB, H2P, EMB, EMBP,
                    nullptr, z0 + r0 * EMBP, z1 + r0 * EMBP, z2 + r0 * EMBP);
        }
    }

    // ================= Phase S: edge scores + topk =================
    // stacked Wu|Wv planes (bias folded into edge_score)
    conv_w<3><<<cdiv(1216 * EMBP, 256), 256, 0, stream>>>(
        att_W1, EMB, H4, EMBP, 1216, wuvp[0], wuvp[1], wuvp[2]);
    conv_w<3><<<cdiv(1216 * EMBP, 256), 256, 0, stream>>>(
        att_W1 + (size_t)EMB * H4, EMB, H4, EMBP, 1216,
        wuvp[0] + (size_t)1216 * EMBP, wuvp[1] + (size_t)1216 * EMBP,
        wuvp[2] + (size_t)1216 * EMBP);
    for (int sc = 0; sc < 8; ++sc) {
        size_t nb0 = (size_t)sc * 2500;
        mfma_gemm<3, 0, 0><<<dim3(UVM / 64, 20), 256, 0, stream>>>(
            z0 + nb0 * EMBP, z1 + nb0 * EMBP, z2 + nb0 * EMBP,
            wuvp[0], wuvp[1], wuvp[2], nullptr, EMBP, UVM, UVM,
            uvbuf, nullptr, nullptr, nullptr);
        edge_score<<<cdiv(12500, 4), 256, 0, stream>>>(
            uvbuf, att_b1, att_W2, att_b2, src + sc * 12500, dst + sc * 12500,
            score + sc * 12500, 12500, (int)nb0);
    }
    hipMemsetAsync(mask, 0, N_NODES * 4, stream);
    topk_kernel<<<N_GRAPHS, 512, 0, stream>>>(score, src, dst, c_src, c_dst, c_w, mask);

    // ================= Phase C: classifier (NT=2) =================
    conv_w<2><<<(EMBP * 64) / 256, 256, 0, stream>>>(clf_in_W, D_IN, EMB, 64, EMBP,
                                                     w0p[0], w0p[1], w0p[2]);
    conv_a<2><<<(int)(((long)NPAD * 64) / 256), 256, 0, stream>>>(
        x, N_NODES, D_IN, D_IN, 64, xp[0], xp[1], xp[2], (long)NPAD * 64);
    mfma_gemm<2, 0, 0><<<dim3(EMBP / 64, NPAD / 128), 256, 0, stream>>>(
        xp[0], xp[1], nullptr, w0p[0], w0p[1], nullptr, clf_in_b, 64, EMB, EMBP,
        h, nullptr, nullptr, nullptr);

    hipMemsetAsync(At, 0, (size_t)N_GRAPHS * NPG * NPG * 4, stream);
    build_At<<<cdiv(N_GRAPHS * TOPK, 256), 256, 0, stream>>>(c_src, c_dst, c_w, At,
                                                             N_GRAPHS * TOPK);

    for (int l = 0; l < NLAYERS; ++l) {
        agg_gemm<2><<<dim3(N_GRAPHS, 5), 256, 0, stream>>>(h, At, clf_eps, l,
                                                           z0, z1, nullptr);
        conv_w2<2><<<(2 * H2P * EMBP) / 256, 256, 0, stream>>>(
            clf_W1 + (size_t)l * EMB * H2, clf_W2 + (size_t)l * H2 * EMB,
            w0p[0], w0p[1], nullptr, w1p[0], w1p[1], nullptr);
        for (int c = 0; c < 4; ++c) {
            size_t r0 = (size_t)chunk_start[c] * 128;
            int nb = chunk_nb[c];
            mfma_gemm<2, 1, 1><<<dim3(H2P / 64, nb), 256, 0, stream>>>(
                z0 + r0 * EMBP, z1 + r0 * EMBP, nullptr,
                w0p[0], w0p[1], nullptr, clf_b1 + l * H2, EMBP, H2, H2P,
                nullptr, t0, t1, nullptr);
            if (l < NLAYERS - 1)
                mfma_gemm<2, 1, 0><<<dim3(EMBP / 64, nb), 256, 0, stream>>>(
                    t0, t1, nullptr, w1p[0], w1p[1], nullptr, clf_b2 + l * EMB, H2P, EMB, EMBP,
                    h + r0 * EMBP, nullptr, nullptr, nullptr);
            else
                mfma_gemm<2, 0, 0><<<dim3(EMBP / 64, nb), 256, 0, stream>>>(
                    t0, t1, nullptr, w1p[0], w1p[1], nullptr, clf_b2 + l * EMB, H2P, EMB, EMBP,
                    h + r0 * EMBP, nullptr, nullptr, nullptr);
        }
    }

    // ================= pool + head =================
    pool_pred<<<N_GRAPHS, 256, 0, stream>>>(h, mask, pred_W, pred_b, out);
}

// Round 6
// 2483.590 us; speedup vs baseline: 1.6297x; 1.2074x over previous
//
#include <hip/hip_runtime.h>
#include <hip/hip_bf16.h>
#include <math.h>

#define N_NODES 20000
#define N_EDGES 100000
#define N_GRAPHS 200
#define NPG 100
#define EPG 500
#define TOPK 125
#define D_IN 64
#define EMB 300
#define H2 600
#define H4 1200
#define NLAYERS 5
#define NOUT 10

// padded dims
#define NPAD 20096      // 157 * 128
#define EMBP 320
#define H2P 640
#define H4P 1216
#define UVM 2432        // stacked u|v output width (2*1216)
#define UVROWS 10112    // 79 * 128 rows per uv chunk

static inline int cdiv(int a, int b) { return (a + b - 1) / b; }

typedef __attribute__((ext_vector_type(8))) short bfrag;
typedef __attribute__((ext_vector_type(4))) float f32x4;

__device__ __forceinline__ ushort f2bf(float f) {
    unsigned u = __builtin_bit_cast(unsigned, f);
    unsigned r = u + 0x7FFFu + ((u >> 16) & 1u);
    return (ushort)(r >> 16);
}
__device__ __forceinline__ float bf2f(ushort h) {
    unsigned u = ((unsigned)h) << 16;
    return __builtin_bit_cast(float, u);
}

template<int NT>
__device__ __forceinline__ void split_planes(float v, ushort& p0, ushort& p1, ushort& p2) {
    p0 = f2bf(v);
    float r = v - bf2f(p0);
    p1 = f2bf(r);
    if (NT == 3) { r -= bf2f(p1); p2 = f2bf(r); } else { p2 = 0; }
}

// async 16B global->LDS copy; LDS dest is wave-uniform base (+ lane*16 by HW)
#define GLOAD_LDS16(gsrc, ldst)                                                   \
    __builtin_amdgcn_global_load_lds(                                             \
        (const __attribute__((address_space(1))) void*)(gsrc),                    \
        (__attribute__((address_space(3))) void*)(ldst), 16, 0, 0)

// ============================================================================
// MFMA GEMM (round-3/5 proven structure, byte-identical): A and B staged via
// global_load_lds, 2 barriers per K-step.  BM=128, BN=64, 4 waves (2x2).
// EPI=0: write fp32 C (+bias, opt relu).  EPI=1: write NT bf16 planes.
// ============================================================================
template<int NT, int RELU, int EPI>
__launch_bounds__(256)
__global__ void mfma_gemm(const ushort* __restrict__ A0, const ushort* __restrict__ A1,
                          const ushort* __restrict__ A2,
                          const ushort* __restrict__ B0, const ushort* __restrict__ B1,
                          const ushort* __restrict__ B2,
                          const float* __restrict__ bias, int Kp, int Mvalid, int ldc,
                          float* __restrict__ Cf, ushort* __restrict__ C0,
                          ushort* __restrict__ C1, ushort* __restrict__ C2) {
    __shared__ char smem[NT * 8192 + NT * 4096];   // A planes (128x32x2B) + B planes (64x32x2B)
    const int tid = threadIdx.x;
    const int wave = tid >> 6, lane = tid & 63;
    const int wr = wave >> 1, wc = wave & 1;
    const long rowbase = (long)blockIdx.y * 128;
    const int n0 = blockIdx.x * 64;

    const ushort* Ap[3] = {A0, A1, A2};
    const ushort* Bp[3] = {B0, B1, B2};

    f32x4 acc[4][2] = {};

    // staging geometry (swizzled global source, linear LDS dest)
    const int arow0 = wave * 16 + (lane >> 2);         // A it=0 row; it=1 adds 64
    const int aq = lane & 3;
    const int brow = wave * 16 + (lane >> 2);          // B row (0..63)

    for (int k0 = 0; k0 < Kp; k0 += 32) {
        // ---- stage A planes (2 iters of 4KB) and B planes (1 iter of 4KB)
#pragma unroll
        for (int p = 0; p < NT; ++p) {
            {
                int r = arow0;
                int q = aq ^ ((r >> 1) & 3);
                const ushort* g = Ap[p] + (size_t)(rowbase + r) * Kp + k0 + q * 8;
                GLOAD_LDS16(g, smem + p * 8192 + wave * 1024);
            }
            {
                int r = arow0 + 64;
                int q = aq ^ ((r >> 1) & 3);
                const ushort* g = Ap[p] + (size_t)(rowbase + r) * Kp + k0 + q * 8;
                GLOAD_LDS16(g, smem + p * 8192 + 4096 + wave * 1024);
            }
            {
                int q = aq ^ ((brow >> 1) & 3);
                const ushort* g = Bp[p] + (size_t)(n0 + brow) * Kp + k0 + q * 8;
                GLOAD_LDS16(g, smem + NT * 8192 + p * 4096 + wave * 1024);
            }
        }
        __syncthreads();

        // ---- fragments + MFMA
        bfrag bfr[2][3];
#pragma unroll
        for (int n = 0; n < 2; ++n)
#pragma unroll
            for (int p = 0; p < NT; ++p) {
                int rB = wc * 32 + n * 16 + (lane & 15);
                int q = (lane >> 4) ^ ((rB >> 1) & 3);
                bfr[n][p] = *(const bfrag*)(smem + NT * 8192 + p * 4096 + rB * 64 + q * 16);
            }
#pragma unroll
        for (int m = 0; m < 4; ++m) {
            bfrag afr[3];
#pragma unroll
            for (int p = 0; p < NT; ++p) {
                int rA = wr * 64 + m * 16 + (lane & 15);
                int q = (lane >> 4) ^ ((rA >> 1) & 3);
                afr[p] = *(const bfrag*)(smem + p * 8192 + rA * 64 + q * 16);
            }
#pragma unroll
            for (int n = 0; n < 2; ++n) {
#pragma unroll
                for (int pa = 0; pa < NT; ++pa)
#pragma unroll
                    for (int pb = 0; pb < NT; ++pb)
                        if (pa + pb <= NT - 1)
                            acc[m][n] = __builtin_amdgcn_mfma_f32_16x16x32_bf16(
                                afr[pa], bfr[n][pb], acc[m][n], 0, 0, 0);
            }
        }
        __syncthreads();
    }

    // ---- epilogue.  C/D layout: col = lane&15, row = (lane>>4)*4 + e
    const int colc = lane & 15, rquad = lane >> 4;
#pragma unroll
    for (int m = 0; m < 4; ++m) {
#pragma unroll
        for (int n = 0; n < 2; ++n) {
            long grow0 = rowbase + wr * 64 + m * 16 + rquad * 4;
            int gcol = n0 + wc * 32 + n * 16 + colc;
            bool cvld = gcol < Mvalid;
            float bv = (bias != nullptr && cvld) ? bias[gcol] : 0.f;
#pragma unroll
            for (int e = 0; e < 4; ++e) {
                float v = acc[m][n][e] + bv;
                if (RELU) v = fmaxf(v, 0.f);
                if (!cvld) v = 0.f;
                size_t o = (size_t)(grow0 + e) * ldc + gcol;
                if (EPI == 0) {
                    Cf[o] = v;
                } else {
                    ushort p0, p1, p2;
                    split_planes<NT>(v, p0, p1, p2);
                    C0[o] = p0; C1[o] = p1;
                    if (NT == 3) C2[o] = p2;
                }
            }
        }
    }
}

// ============================================================================
// conversions
// ============================================================================
template<int NT>
__global__ void conv_w(const float* __restrict__ W, int K, int M, int Kp, int Mp,
                       ushort* __restrict__ P0, ushort* __restrict__ P1,
                       ushort* __restrict__ P2) {
    int idx = blockIdx.x * 256 + threadIdx.x;
    if (idx >= Mp * Kp) return;
    int m = idx / Kp, k = idx % Kp;
    float v = (m < M && k < K) ? W[(size_t)k * M + m] : 0.f;
    ushort p0, p1, p2;
    split_planes<NT>(v, p0, p1, p2);
    P0[idx] = p0; P1[idx] = p1;
    if (NT == 3) P2[idx] = p2;
}

// both layer weights (W1: EMB->H2, W2: H2->EMB) in one dispatch
template<int NT>
__global__ void conv_w2(const float* __restrict__ Wa, const float* __restrict__ Wb,
                        ushort* __restrict__ A0, ushort* __restrict__ A1,
                        ushort* __restrict__ A2, ushort* __restrict__ B0,
                        ushort* __restrict__ B1, ushort* __restrict__ B2) {
    int idx = blockIdx.x * 256 + threadIdx.x;
    const int T1 = H2P * EMBP;   // 204800
    if (idx < T1) {
        int m = idx / EMBP, k = idx % EMBP;
        float v = (m < H2 && k < EMB) ? Wa[(size_t)k * H2 + m] : 0.f;
        ushort p0, p1, p2;
        split_planes<NT>(v, p0, p1, p2);
        A0[idx] = p0; A1[idx] = p1;
        if (NT == 3) A2[idx] = p2;
    } else if (idx < 2 * T1) {
        idx -= T1;
        int m = idx / H2P, k = idx % H2P;
        float v = (m < EMB && k < H2) ? Wb[(size_t)k * EMB + m] : 0.f;
        ushort p0, p1, p2;
        split_planes<NT>(v, p0, p1, p2);
        B0[idx] = p0; B1[idx] = p1;
        if (NT == 3) B2[idx] = p2;
    }
}

template<int NT>
__global__ void conv_a(const float* __restrict__ X, int rows_valid, int ldx, int Kv, int Kp,
                       ushort* __restrict__ P0, ushort* __restrict__ P1,
                       ushort* __restrict__ P2, long total) {
    long idx = (long)blockIdx.x * 256 + threadIdx.x;
    if (idx >= total) return;
    int r = (int)(idx / Kp), k = (int)(idx % Kp);
    float v = (r < rows_valid && k < Kv) ? X[(size_t)r * ldx + k] : 0.f;
    ushort p0, p1, p2;
    split_planes<NT>(v, p0, p1, p2);
    P0[idx] = p0; P1[idx] = p1;
    if (NT == 3) P2[idx] = p2;
}

// ============================================================================
// adjacency build (transposed: At[g][src_local][dst_local] += w)
// ============================================================================
__global__ void build_At(const int* __restrict__ src, const int* __restrict__ dst,
                         const float* __restrict__ w, float* __restrict__ At, int E) {
    int e = blockIdx.x * 256 + threadIdx.x;
    if (e >= E) return;
    int s = src[e], d = dst[e];
    int g = s / NPG;
    atomicAdd(&At[(size_t)g * NPG * NPG + (size_t)(s - g * NPG) * NPG + (d - g * NPG)],
              w ? w[e] : 1.f);
}

// ============================================================================
// fused aggregation (round-3 proven, byte-identical): z = At^T h + (1+eps) h,
// NT bf16 planes.  grid = (graph, col-strip of 64); 4 waves x 25 rows each.
// ============================================================================
template<int NT>
__launch_bounds__(256)
__global__ void agg_gemm(const float* __restrict__ h, const float* __restrict__ At,
                         const float* __restrict__ eps, int l,
                         ushort* __restrict__ z0, ushort* __restrict__ z1,
                         ushort* __restrict__ z2) {
    int g = blockIdx.x;
    int strip = blockIdx.y;
    int lane = threadIdx.x & 63;
    int rb = __builtin_amdgcn_readfirstlane((threadIdx.x >> 6) * 25);
    const float* Ag = At + (size_t)g * NPG * NPG;
    const float* hg = h + (size_t)g * NPG * EMBP;
    float ep = 1.f + eps[l];

    int c = strip * 64 + lane;
    bool cv = c < EMB;
    float acc[25];
#pragma unroll
    for (int r = 0; r < 25; ++r) acc[r] = 0.f;
#pragma unroll 4
    for (int k = 0; k < NPG; ++k) {
        float hv = cv ? hg[k * EMBP + c] : 0.f;
        const float* ak = Ag + k * NPG + rb;
#pragma unroll
        for (int r = 0; r < 25; ++r) acc[r] += ak[r] * hv;
    }
#pragma unroll
    for (int r = 0; r < 25; ++r) {
        int row = g * NPG + rb + r;
        float z = cv ? acc[r] + ep * hg[(rb + r) * EMBP + c] : 0.f;
        ushort p0, p1, p2;
        split_planes<NT>(z, p0, p1, p2);
        size_t o = (size_t)row * EMBP + c;
        z0[o] = p0; z1[o] = p1;
        if (NT == 3) z2[o] = p2;
    }
}

// ============================================================================
// edge score from stacked uv buffer: relu(u[src]+v[dst]+b1) . W2 + b2
// uv row layout: [0:1216) = u, [1216:2432) = v
// ============================================================================
__global__ void edge_score(const float* __restrict__ uv, const float* __restrict__ b1,
                           const float* __restrict__ W2, const float* __restrict__ b2,
                           const int* __restrict__ src, const int* __restrict__ dst,
                           float* __restrict__ score, int E, int node_base) {
    int e = blockIdx.x * 4 + (threadIdx.x >> 6);
    int lane = threadIdx.x & 63;
    if (e >= E) return;
    const float* up = uv + (size_t)(src[e] - node_base) * UVM;
    const float* vp = uv + (size_t)(dst[e] - node_base) * UVM + 1216;
    float acc = 0.f;
    for (int j = lane; j < H4; j += 64) {
        float hj = fmaxf(up[j] + vp[j] + b1[j], 0.f);
        acc += hj * W2[j];
    }
#pragma unroll
    for (int o = 32; o > 0; o >>= 1) acc += __shfl_down(acc, o, 64);
    if (lane == 0) score[e] = acc + b2[0];
}

// ============================================================================
// per-graph top-125 of 500 contiguous edges via bitonic sort
// ============================================================================
__global__ void topk_kernel(const float* __restrict__ score, const int* __restrict__ src,
                            const int* __restrict__ dst, int* __restrict__ c_src,
                            int* __restrict__ c_dst, float* __restrict__ c_w,
                            float* __restrict__ mask) {
    __shared__ float s[512];
    __shared__ short sidx[512];
    int g = blockIdx.x, t = threadIdx.x;
    int base = g * EPG;
    s[t] = (t < EPG) ? score[base + t] : -1e30f;
    sidx[t] = (short)t;
    __syncthreads();
    for (int k = 2; k <= 512; k <<= 1) {
        for (int j = k >> 1; j > 0; j >>= 1) {
            int ixj = t ^ j;
            if (ixj > t) {
                float a = s[t], b = s[ixj];
                bool desc = ((t & k) == 0);
                if (desc ? (a < b) : (a > b)) {
                    s[t] = b; s[ixj] = a;
                    short tmp = sidx[t]; sidx[t] = sidx[ixj]; sidx[ixj] = tmp;
                }
            }
            __syncthreads();
        }
    }
    if (t < TOPK) {
        int e = base + sidx[t];
        int sn = src[e], dn = dst[e];
        c_src[g * TOPK + t] = sn;
        c_dst[g * TOPK + t] = dn;
        c_w[g * TOPK + t] = 1.f / (1.f + expf(-s[t]));
        mask[sn] = 1.f;
        mask[dn] = 1.f;
    }
}

// ============================================================================
// masked mean pool + linear head (h stride EMBP)
// ============================================================================
__global__ void pool_pred(const float* __restrict__ hc, const float* __restrict__ mask,
                          const float* __restrict__ W, const float* __restrict__ b,
                          float* __restrict__ out) {
    int g = blockIdx.x, t = threadIdx.x;
    __shared__ float mloc[NPG];
    __shared__ float pooled[EMB];
    __shared__ float cnt;
    if (t < NPG) mloc[t] = mask[g * NPG + t];
    __syncthreads();
    if (t == 0) {
        float c = 0.f;
        for (int n = 0; n < NPG; ++n) c += mloc[n];
        cnt = fmaxf(c, 1.f);
    }
    __syncthreads();
    for (int c0 = t; c0 < EMB; c0 += 256) {
        float acc = 0.f;
        for (int n = 0; n < NPG; ++n)
            acc += mloc[n] * hc[((size_t)g * NPG + n) * EMBP + c0];
        pooled[c0] = acc / cnt;
    }
    __syncthreads();
    if (t < NOUT) {
        float acc = b[t];
        for (int c0 = 0; c0 < EMB; ++c0) acc += pooled[c0] * W[c0 * NOUT + t];
        out[g * NOUT + t] = acc;
    }
}

// ============================================================================
extern "C" void kernel_launch(void* const* d_in, const int* in_sizes, int n_in,
                              void* d_out, int out_size, void* d_ws, size_t ws_size,
                              hipStream_t stream) {
    const float* x        = (const float*)d_in[0];
    const int*   eidx     = (const int*)d_in[1];
    const float* enc_in_W = (const float*)d_in[4];
    const float* enc_in_b = (const float*)d_in[5];
    const float* enc_W1   = (const float*)d_in[6];
    const float* enc_b1   = (const float*)d_in[7];
    const float* enc_W2   = (const float*)d_in[8];
    const float* enc_b2   = (const float*)d_in[9];
    const float* enc_eps  = (const float*)d_in[10];
    const float* att_W1   = (const float*)d_in[11];
    const float* att_b1   = (const float*)d_in[12];
    const float* att_W2   = (const float*)d_in[13];
    const float* att_b2   = (const float*)d_in[14];
    const float* clf_in_W = (const float*)d_in[15];
    const float* clf_in_b = (const float*)d_in[16];
    const float* clf_W1   = (const float*)d_in[17];
    const float* clf_b1   = (const float*)d_in[18];
    const float* clf_W2   = (const float*)d_in[19];
    const float* clf_b2   = (const float*)d_in[20];
    const float* clf_eps  = (const float*)d_in[21];
    const float* pred_W   = (const float*)d_in[22];
    const float* pred_b   = (const float*)d_in[23];
    float* out = (float*)d_out;

    const int* src = eidx;
    const int* dst = eidx + N_EDGES;

    // ---------------- workspace layout (ws_size = 256 MiB per harness poison) ----
    char* ws = (char*)d_ws;
    constexpr size_t SZ_H    = (size_t)NPAD * EMBP * 4;        //  25,722,880
    constexpr size_t SZ_ZP   = (size_t)NPAD * EMBP * 2;        //  12,861,440 per plane
    constexpr size_t SZ_TP   = (size_t)NPAD * H2P * 2;         //  25,722,880 per plane (FULL)
    constexpr size_t SZ_WSP  = (size_t)H2P * EMBP * 2;         //     409,600 per plane
    constexpr size_t SZ_WUVP = (size_t)UVM * EMBP * 2;         //   1,556,480 per plane

    constexpr size_t OFF_H   = 0;
    constexpr size_t OFF_Z   = OFF_H + SZ_H;                   //  25,722,880
    constexpr size_t OFF_T   = OFF_Z + 3 * SZ_ZP;              //  64,307,200
    constexpr size_t OFF_WSL = OFF_T + 3 * SZ_TP;              // 141,475,840
    constexpr size_t OFF_AT  = OFF_WSL + 6 * SZ_WSP;           // 143,933,440
    constexpr size_t OFF_SC  = OFF_AT + (size_t)N_GRAPHS * NPG * NPG * 4;  // 151,933,440
    constexpr size_t OFF_CW  = OFF_SC + (size_t)N_EDGES * 4;
    constexpr size_t OFF_MK  = OFF_CW + (size_t)N_GRAPHS * TOPK * 4;
    constexpr size_t OFF_CS  = OFF_MK + (size_t)N_NODES * 4;
    constexpr size_t OFF_CD  = OFF_CS + (size_t)N_GRAPHS * TOPK * 4;
    constexpr size_t OFF_UV  = OFF_CD + (size_t)N_GRAPHS * TOPK * 4;       // 152,713,440
    // uvbuf = UVROWS x UVM x 4 = 98,369,536 -> high water 251,082,976 < 256 MiB

    float*  h   = (float*)(ws + OFF_H);
    ushort* z0  = (ushort*)(ws + OFF_Z);
    ushort* z1  = (ushort*)(ws + OFF_Z + SZ_ZP);
    ushort* z2  = (ushort*)(ws + OFF_Z + 2 * SZ_ZP);
    ushort* t0  = (ushort*)(ws + OFF_T);
    ushort* t1  = (ushort*)(ws + OFF_T + SZ_TP);
    ushort* t2  = (ushort*)(ws + OFF_T + 2 * SZ_TP);
    ushort* w0p[3] = {(ushort*)(ws + OFF_WSL), (ushort*)(ws + OFF_WSL + SZ_WSP),
                      (ushort*)(ws + OFF_WSL + 2 * SZ_WSP)};
    ushort* w1p[3] = {(ushort*)(ws + OFF_WSL + 3 * SZ_WSP), (ushort*)(ws + OFF_WSL + 4 * SZ_WSP),
                      (ushort*)(ws + OFF_WSL + 5 * SZ_WSP)};
    float*  At    = (float*)(ws + OFF_AT);
    float*  score = (float*)(ws + OFF_SC);
    float*  c_w   = (float*)(ws + OFF_CW);
    float*  mask  = (float*)(ws + OFF_MK);
    int*    c_src = (int*)(ws + OFF_CS);
    int*    c_dst = (int*)(ws + OFF_CD);
    float*  uvbuf = (float*)(ws + OFF_UV);

    // overlays
    ushort* xp[3] = {z0, z1, z2};              // x planes live in z region pre-layers
    // phase S: wuv planes live in the (dead) t region
    ushort* wuvp[3] = {(ushort*)(ws + OFF_T), (ushort*)(ws + OFF_T + SZ_WUVP),
                       (ushort*)(ws + OFF_T + 2 * SZ_WUVP)};

    // ================= Phase E: encoder (NT=3) =================
    conv_w<3><<<(EMBP * 64) / 256, 256, 0, stream>>>(enc_in_W, D_IN, EMB, 64, EMBP,
                                                     w0p[0], w0p[1], w0p[2]);
    conv_a<3><<<(int)(((long)NPAD * 64) / 256), 256, 0, stream>>>(
        x, N_NODES, D_IN, D_IN, 64, xp[0], xp[1], xp[2], (long)NPAD * 64);
    mfma_gemm<3, 0, 0><<<dim3(EMBP / 64, NPAD / 128), 256, 0, stream>>>(
        xp[0], xp[1], xp[2], w0p[0], w0p[1], w0p[2], enc_in_b, 64, EMB, EMBP,
        h, nullptr, nullptr, nullptr);

    hipMemsetAsync(At, 0, (size_t)N_GRAPHS * NPG * NPG * 4, stream);
    build_At<<<cdiv(N_EDGES, 256), 256, 0, stream>>>(src, dst, nullptr, At, N_EDGES);

    for (int l = 0; l < NLAYERS; ++l) {
        agg_gemm<3><<<dim3(N_GRAPHS, 5), 256, 0, stream>>>(h, At, enc_eps, l, z0, z1, z2);
        conv_w2<3><<<(2 * H2P * EMBP) / 256, 256, 0, stream>>>(
            enc_W1 + (size_t)l * EMB * H2, enc_W2 + (size_t)l * H2 * EMB,
            w0p[0], w0p[1], w0p[2], w1p[0], w1p[1], w1p[2]);
        mfma_gemm<3, 1, 1><<<dim3(H2P / 64, NPAD / 128), 256, 0, stream>>>(
            z0, z1, z2, w0p[0], w0p[1], w0p[2], enc_b1 + l * H2, EMBP, H2, H2P,
            nullptr, t0, t1, t2);
        if (l < NLAYERS - 1)
            mfma_gemm<3, 1, 0><<<dim3(EMBP / 64, NPAD / 128), 256, 0, stream>>>(
                t0, t1, t2, w1p[0], w1p[1], w1p[2], enc_b2 + l * EMB, H2P, EMB, EMBP,
                h, nullptr, nullptr, nullptr);
        else   // final layer: emit bf16 planes (no relu) straight into z region
            mfma_gemm<3, 0, 1><<<dim3(EMBP / 64, NPAD / 128), 256, 0, stream>>>(
                t0, t1, t2, w1p[0], w1p[1], w1p[2], enc_b2 + l * EMB, H2P, EMB, EMBP,
                nullptr, z0, z1, z2);
    }

    // ================= Phase S: edge scores + topk (2 chunks) =================
    // stacked Wu|Wv planes (bias folded into edge_score)
    conv_w<3><<<cdiv(1216 * EMBP, 256), 256, 0, stream>>>(
        att_W1, EMB, H4, EMBP, 1216, wuvp[0], wuvp[1], wuvp[2]);
    conv_w<3><<<cdiv(1216 * EMBP, 256), 256, 0, stream>>>(
        att_W1 + (size_t)EMB * H4, EMB, H4, EMBP, 1216,
        wuvp[0] + (size_t)1216 * EMBP, wuvp[1] + (size_t)1216 * EMBP,
        wuvp[2] + (size_t)1216 * EMBP);
    for (int sc = 0; sc < 2; ++sc) {
        size_t nb0 = (size_t)sc * 10000;           // node base (0 / 10000)
        // rows nb0..nb0+10112 cover all nodes of this chunk's graphs; the few
        // OOB rows past NPAD read mapped ws (finite bf16) and feed unused uv rows.
        mfma_gemm<3, 0, 0><<<dim3(UVM / 64, UVROWS / 128), 256, 0, stream>>>(
            z0 + nb0 * EMBP, z1 + nb0 * EMBP, z2 + nb0 * EMBP,
            wuvp[0], wuvp[1], wuvp[2], nullptr, EMBP, UVM, UVM,
            uvbuf, nullptr, nullptr, nullptr);
        edge_score<<<cdiv(N_EDGES / 2, 4), 256, 0, stream>>>(
            uvbuf, att_b1, att_W2, att_b2, src + sc * 50000, dst + sc * 50000,
            score + sc * 50000, N_EDGES / 2, (int)nb0);
    }
    hipMemsetAsync(mask, 0, N_NODES * 4, stream);
    topk_kernel<<<N_GRAPHS, 512, 0, stream>>>(score, src, dst, c_src, c_dst, c_w, mask);

    // ================= Phase C: classifier (NT=2) =================
    conv_w<2><<<(EMBP * 64) / 256, 256, 0, stream>>>(clf_in_W, D_IN, EMB, 64, EMBP,
                                                     w0p[0], w0p[1], w0p[2]);
    conv_a<2><<<(int)(((long)NPAD * 64) / 256), 256, 0, stream>>>(
        x, N_NODES, D_IN, D_IN, 64, xp[0], xp[1], nullptr, (long)NPAD * 64);
    mfma_gemm<2, 0, 0><<<dim3(EMBP / 64, NPAD / 128), 256, 0, stream>>>(
        xp[0], xp[1], nullptr, w0p[0], w0p[1], nullptr, clf_in_b, 64, EMB, EMBP,
        h, nullptr, nullptr, nullptr);

    hipMemsetAsync(At, 0, (size_t)N_GRAPHS * NPG * NPG * 4, stream);
    build_At<<<cdiv(N_GRAPHS * TOPK, 256), 256, 0, stream>>>(c_src, c_dst, c_w, At,
                                                             N_GRAPHS * TOPK);

    for (int l = 0; l < NLAYERS; ++l) {
        agg_gemm<2><<<dim3(N_GRAPHS, 5), 256, 0, stream>>>(h, At, clf_eps, l,
                                                           z0, z1, nullptr);
        conv_w2<2><<<(2 * H2P * EMBP) / 256, 256, 0, stream>>>(
            clf_W1 + (size_t)l * EMB * H2, clf_W2 + (size_t)l * H2 * EMB,
            w0p[0], w0p[1], nullptr, w1p[0], w1p[1], nullptr);
        mfma_gemm<2, 1, 1><<<dim3(H2P / 64, NPAD / 128), 256, 0, stream>>>(
            z0, z1, nullptr, w0p[0], w0p[1], nullptr, clf_b1 + l * H2, EMBP, H2, H2P,
            nullptr, t0, t1, nullptr);
        if (l < NLAYERS - 1)
            mfma_gemm<2, 1, 0><<<dim3(EMBP / 64, NPAD / 128), 256, 0, stream>>>(
                t0, t1, nullptr, w1p[0], w1p[1], nullptr, clf_b2 + l * EMB, H2P, EMB, EMBP,
                h, nullptr, nullptr, nullptr);
        else
            mfma_gemm<2, 0, 0><<<dim3(EMBP / 64, NPAD / 128), 256, 0, stream>>>(
                t0, t1, nullptr, w1p[0], w1p[1], nullptr, clf_b2 + l * EMB, H2P, EMB, EMBP,
                h, nullptr, nullptr, nullptr);
    }

    // ================= pool + head =================
    pool_pred<<<N_GRAPHS, 256, 0, stream>>>(h, mask, pred_W, pred_b, out);
}

// Round 7
// 1989.931 us; speedup vs baseline: 2.0340x; 1.2481x over previous
//
#include <hip/hip_runtime.h>
#include <hip/hip_bf16.h>
#include <math.h>

#define N_NODES 20000
#define N_EDGES 100000
#define N_GRAPHS 200
#define NPG 100
#define EPG 500
#define TOPK 125
#define D_IN 64
#define EMB 300
#define H2 600
#define H4 1200
#define NLAYERS 5
#define NOUT 10

// padded dims
#define NPAD 20096      // 157 * 128
#define EMBP 320
#define H2P 640
#define H4P 1216
#define UVM 2432        // stacked u|v output width (2*1216)
#define UVROWS 10112    // 79 * 128 rows per uv chunk

static inline int cdiv(int a, int b) { return (a + b - 1) / b; }

typedef __attribute__((ext_vector_type(8))) short bfrag;
typedef __attribute__((ext_vector_type(4))) float f32x4;

__device__ __forceinline__ ushort f2bf(float f) {
    unsigned u = __builtin_bit_cast(unsigned, f);
    unsigned r = u + 0x7FFFu + ((u >> 16) & 1u);
    return (ushort)(r >> 16);
}
__device__ __forceinline__ float bf2f(ushort h) {
    unsigned u = ((unsigned)h) << 16;
    return __builtin_bit_cast(float, u);
}

template<int NT>
__device__ __forceinline__ void split_planes(float v, ushort& p0, ushort& p1, ushort& p2) {
    p0 = f2bf(v);
    float r = v - bf2f(p0);
    p1 = f2bf(r);
    if (NT == 3) { r -= bf2f(p1); p2 = f2bf(r); } else { p2 = 0; }
}

// async 16B global->LDS copy; LDS dest is wave-uniform base (+ lane*16 by HW)
#define GLOAD_LDS16(gsrc, ldst)                                                   \
    __builtin_amdgcn_global_load_lds(                                             \
        (const __attribute__((address_space(1))) void*)(gsrc),                    \
        (__attribute__((address_space(3))) void*)(ldst), 16, 0, 0)

// ============================================================================
// MFMA GEMM.  A and B staged via global_load_lds, 2 barriers per K-step.
// BM=128, BN=64 or 128, 4 waves (2x2); per-wave 64 rows x BN/2 cols.
// XCD-aware bijective block remap: all column-blocks of a row-panel run on the
// same XCD so the A panel is fetched from HBM once (was ~4.6x over-fetch).
// EPI=0: write fp32 C (+bias, opt relu).  EPI=1: write NT bf16 planes.
// Arithmetic identical to round-5/6 kernel (same products, same K order).
// ============================================================================
template<int NT, int RELU, int EPI, int BN>
__launch_bounds__(256)
__global__ void mfma_gemm(const ushort* __restrict__ A0, const ushort* __restrict__ A1,
                          const ushort* __restrict__ A2,
                          const ushort* __restrict__ B0, const ushort* __restrict__ B1,
                          const ushort* __restrict__ B2,
                          const float* __restrict__ bias, int Kp, int Mvalid, int ldc,
                          float* __restrict__ Cf, ushort* __restrict__ C0,
                          ushort* __restrict__ C1, ushort* __restrict__ C2) {
    constexpr int NCOL   = BN / 32;        // per-wave n-fragments (2 or 4)
    constexpr int ABYTES = 8192;           // per plane A tile: 128x32x2B
    constexpr int BBYTES = BN * 64;        // per plane B tile: BNx32x2B
    __shared__ char smem[NT * ABYTES + NT * BBYTES];
    const int tid = threadIdx.x;
    const int wave = tid >> 6, lane = tid & 63;
    const int wr = wave >> 1, wc = wave & 1;

    // ---- bijective XCD remap (col-fastest within an XCD's contiguous range)
    int bx, by;
    {
        const int gx = gridDim.x;
        const int nwg = gx * gridDim.y;
        const int wg = blockIdx.y * gx + blockIdx.x;
        const int q = nwg >> 3, rch = nwg & 7;
        const int xc = wg & 7, k = wg >> 3;
        const int virt = (xc < rch ? xc * (q + 1) : rch * (q + 1) + (xc - rch) * q) + k;
        bx = virt % gx;
        by = virt / gx;
    }
    const long rowbase = (long)by * 128;
    const int n0 = bx * BN;

    const ushort* Ap[3] = {A0, A1, A2};
    const ushort* Bp[3] = {B0, B1, B2};

    f32x4 acc[4][NCOL] = {};

    // staging geometry (swizzled global source, linear LDS dest)
    const int arow0 = wave * 16 + (lane >> 2);
    const int aq = lane & 3;

    for (int k0 = 0; k0 < Kp; k0 += 32) {
        // ---- stage A planes (2x4KB) and B planes (1 or 2 x4KB)
#pragma unroll
        for (int p = 0; p < NT; ++p) {
            {
                int r = arow0;
                int q = aq ^ ((r >> 1) & 3);
                GLOAD_LDS16(Ap[p] + (size_t)(rowbase + r) * Kp + k0 + q * 8,
                            smem + p * ABYTES + wave * 1024);
            }
            {
                int r = arow0 + 64;
                int q = aq ^ ((r >> 1) & 3);
                GLOAD_LDS16(Ap[p] + (size_t)(rowbase + r) * Kp + k0 + q * 8,
                            smem + p * ABYTES + 4096 + wave * 1024);
            }
            {
                int r = arow0;
                int q = aq ^ ((r >> 1) & 3);
                GLOAD_LDS16(Bp[p] + (size_t)(n0 + r) * Kp + k0 + q * 8,
                            smem + NT * ABYTES + p * BBYTES + wave * 1024);
            }
            if (BN == 128) {
                int r = arow0 + 64;
                int q = aq ^ ((r >> 1) & 3);
                GLOAD_LDS16(Bp[p] + (size_t)(n0 + r) * Kp + k0 + q * 8,
                            smem + NT * ABYTES + p * BBYTES + 4096 + wave * 1024);
            }
        }
        __syncthreads();

        // ---- fragments + MFMA
        bfrag bfr[NCOL][3];
#pragma unroll
        for (int n = 0; n < NCOL; ++n)
#pragma unroll
            for (int p = 0; p < NT; ++p) {
                int rB = wc * (BN / 2) + n * 16 + (lane & 15);
                int q = (lane >> 4) ^ ((rB >> 1) & 3);
                bfr[n][p] = *(const bfrag*)(smem + NT * ABYTES + p * BBYTES + rB * 64 + q * 16);
            }
#pragma unroll
        for (int m = 0; m < 4; ++m) {
            bfrag afr[3];
#pragma unroll
            for (int p = 0; p < NT; ++p) {
                int rA = wr * 64 + m * 16 + (lane & 15);
                int q = (lane >> 4) ^ ((rA >> 1) & 3);
                afr[p] = *(const bfrag*)(smem + p * ABYTES + rA * 64 + q * 16);
            }
#pragma unroll
            for (int n = 0; n < NCOL; ++n) {
#pragma unroll
                for (int pa = 0; pa < NT; ++pa)
#pragma unroll
                    for (int pb = 0; pb < NT; ++pb)
                        if (pa + pb <= NT - 1)
                            acc[m][n] = __builtin_amdgcn_mfma_f32_16x16x32_bf16(
                                afr[pa], bfr[n][pb], acc[m][n], 0, 0, 0);
            }
        }
        __syncthreads();
    }

    // ---- epilogue.  C/D layout: col = lane&15, row = (lane>>4)*4 + e
    const int colc = lane & 15, rquad = lane >> 4;
#pragma unroll
    for (int m = 0; m < 4; ++m) {
#pragma unroll
        for (int n = 0; n < NCOL; ++n) {
            long grow0 = rowbase + wr * 64 + m * 16 + rquad * 4;
            int gcol = n0 + wc * (BN / 2) + n * 16 + colc;
            bool cvld = gcol < Mvalid;
            float bv = (bias != nullptr && cvld) ? bias[gcol] : 0.f;
#pragma unroll
            for (int e = 0; e < 4; ++e) {
                float v = acc[m][n][e] + bv;
                if (RELU) v = fmaxf(v, 0.f);
                if (!cvld) v = 0.f;
                size_t o = (size_t)(grow0 + e) * ldc + gcol;
                if (EPI == 0) {
                    Cf[o] = v;
                } else {
                    ushort p0, p1, p2;
                    split_planes<NT>(v, p0, p1, p2);
                    C0[o] = p0; C1[o] = p1;
                    if (NT == 3) C2[o] = p2;
                }
            }
        }
    }
}

// ============================================================================
// conversions
// ============================================================================
template<int NT>
__global__ void conv_w(const float* __restrict__ W, int K, int M, int Kp, int Mp,
                       ushort* __restrict__ P0, ushort* __restrict__ P1,
                       ushort* __restrict__ P2) {
    int idx = blockIdx.x * 256 + threadIdx.x;
    if (idx >= Mp * Kp) return;
    int m = idx / Kp, k = idx % Kp;
    float v = (m < M && k < K) ? W[(size_t)k * M + m] : 0.f;
    ushort p0, p1, p2;
    split_planes<NT>(v, p0, p1, p2);
    P0[idx] = p0; P1[idx] = p1;
    if (NT == 3) P2[idx] = p2;
}

// both layer weights (W1: EMB->H2, W2: H2->EMB) in one dispatch
template<int NT>
__global__ void conv_w2(const float* __restrict__ Wa, const float* __restrict__ Wb,
                        ushort* __restrict__ A0, ushort* __restrict__ A1,
                        ushort* __restrict__ A2, ushort* __restrict__ B0,
                        ushort* __restrict__ B1, ushort* __restrict__ B2) {
    int idx = blockIdx.x * 256 + threadIdx.x;
    const int T1 = H2P * EMBP;   // 204800
    if (idx < T1) {
        int m = idx / EMBP, k = idx % EMBP;
        float v = (m < H2 && k < EMB) ? Wa[(size_t)k * H2 + m] : 0.f;
        ushort p0, p1, p2;
        split_planes<NT>(v, p0, p1, p2);
        A0[idx] = p0; A1[idx] = p1;
        if (NT == 3) A2[idx] = p2;
    } else if (idx < 2 * T1) {
        idx -= T1;
        int m = idx / H2P, k = idx % H2P;
        float v = (m < EMB && k < H2) ? Wb[(size_t)k * EMB + m] : 0.f;
        ushort p0, p1, p2;
        split_planes<NT>(v, p0, p1, p2);
        B0[idx] = p0; B1[idx] = p1;
        if (NT == 3) B2[idx] = p2;
    }
}

template<int NT>
__global__ void conv_a(const float* __restrict__ X, int rows_valid, int ldx, int Kv, int Kp,
                       ushort* __restrict__ P0, ushort* __restrict__ P1,
                       ushort* __restrict__ P2, long total) {
    long idx = (long)blockIdx.x * 256 + threadIdx.x;
    if (idx >= total) return;
    int r = (int)(idx / Kp), k = (int)(idx % Kp);
    float v = (r < rows_valid && k < Kv) ? X[(size_t)r * ldx + k] : 0.f;
    ushort p0, p1, p2;
    split_planes<NT>(v, p0, p1, p2);
    P0[idx] = p0; P1[idx] = p1;
    if (NT == 3) P2[idx] = p2;
}

// ============================================================================
// adjacency build (transposed: At[g][src_local][dst_local] += w)
// ============================================================================
__global__ void build_At(const int* __restrict__ src, const int* __restrict__ dst,
                         const float* __restrict__ w, float* __restrict__ At, int E) {
    int e = blockIdx.x * 256 + threadIdx.x;
    if (e >= E) return;
    int s = src[e], d = dst[e];
    int g = s / NPG;
    atomicAdd(&At[(size_t)g * NPG * NPG + (size_t)(s - g * NPG) * NPG + (d - g * NPG)],
              w ? w[e] : 1.f);
}

// ============================================================================
// fused aggregation (round-3 proven, byte-identical): z = At^T h + (1+eps) h,
// NT bf16 planes.  grid = (graph, col-strip of 64); 4 waves x 25 rows each.
// ============================================================================
template<int NT>
__launch_bounds__(256)
__global__ void agg_gemm(const float* __restrict__ h, const float* __restrict__ At,
                         const float* __restrict__ eps, int l,
                         ushort* __restrict__ z0, ushort* __restrict__ z1,
                         ushort* __restrict__ z2) {
    int g = blockIdx.x;
    int strip = blockIdx.y;
    int lane = threadIdx.x & 63;
    int rb = __builtin_amdgcn_readfirstlane((threadIdx.x >> 6) * 25);
    const float* Ag = At + (size_t)g * NPG * NPG;
    const float* hg = h + (size_t)g * NPG * EMBP;
    float ep = 1.f + eps[l];

    int c = strip * 64 + lane;
    bool cv = c < EMB;
    float acc[25];
#pragma unroll
    for (int r = 0; r < 25; ++r) acc[r] = 0.f;
#pragma unroll 4
    for (int k = 0; k < NPG; ++k) {
        float hv = cv ? hg[k * EMBP + c] : 0.f;
        const float* ak = Ag + k * NPG + rb;
#pragma unroll
        for (int r = 0; r < 25; ++r) acc[r] += ak[r] * hv;
    }
#pragma unroll
    for (int r = 0; r < 25; ++r) {
        int row = g * NPG + rb + r;
        float z = cv ? acc[r] + ep * hg[(rb + r) * EMBP + c] : 0.f;
        ushort p0, p1, p2;
        split_planes<NT>(z, p0, p1, p2);
        size_t o = (size_t)row * EMBP + c;
        z0[o] = p0; z1[o] = p1;
        if (NT == 3) z2[o] = p2;
    }
}

// ============================================================================
// edge score from stacked uv buffer: relu(u[src]+v[dst]+b1) . W2 + b2
// uv row layout: [0:1216) = u, [1216:2432) = v
// ============================================================================
__global__ void edge_score(const float* __restrict__ uv, const float* __restrict__ b1,
                           const float* __restrict__ W2, const float* __restrict__ b2,
                           const int* __restrict__ src, const int* __restrict__ dst,
                           float* __restrict__ score, int E, int node_base) {
    int e = blockIdx.x * 4 + (threadIdx.x >> 6);
    int lane = threadIdx.x & 63;
    if (e >= E) return;
    const float* up = uv + (size_t)(src[e] - node_base) * UVM;
    const float* vp = uv + (size_t)(dst[e] - node_base) * UVM + 1216;
    float acc = 0.f;
    for (int j = lane; j < H4; j += 64) {
        float hj = fmaxf(up[j] + vp[j] + b1[j], 0.f);
        acc += hj * W2[j];
    }
#pragma unroll
    for (int o = 32; o > 0; o >>= 1) acc += __shfl_down(acc, o, 64);
    if (lane == 0) score[e] = acc + b2[0];
}

// ============================================================================
// per-graph top-125 of 500 contiguous edges via bitonic sort
// ============================================================================
__global__ void topk_kernel(const float* __restrict__ score, const int* __restrict__ src,
                            const int* __restrict__ dst, int* __restrict__ c_src,
                            int* __restrict__ c_dst, float* __restrict__ c_w,
                            float* __restrict__ mask) {
    __shared__ float s[512];
    __shared__ short sidx[512];
    int g = blockIdx.x, t = threadIdx.x;
    int base = g * EPG;
    s[t] = (t < EPG) ? score[base + t] : -1e30f;
    sidx[t] = (short)t;
    __syncthreads();
    for (int k = 2; k <= 512; k <<= 1) {
        for (int j = k >> 1; j > 0; j >>= 1) {
            int ixj = t ^ j;
            if (ixj > t) {
                float a = s[t], b = s[ixj];
                bool desc = ((t & k) == 0);
                if (desc ? (a < b) : (a > b)) {
                    s[t] = b; s[ixj] = a;
                    short tmp = sidx[t]; sidx[t] = sidx[ixj]; sidx[ixj] = tmp;
                }
            }
            __syncthreads();
        }
    }
    if (t < TOPK) {
        int e = base + sidx[t];
        int sn = src[e], dn = dst[e];
        c_src[g * TOPK + t] = sn;
        c_dst[g * TOPK + t] = dn;
        c_w[g * TOPK + t] = 1.f / (1.f + expf(-s[t]));
        mask[sn] = 1.f;
        mask[dn] = 1.f;
    }
}

// ============================================================================
// masked mean pool + linear head (h stride EMBP)
// ============================================================================
__global__ void pool_pred(const float* __restrict__ hc, const float* __restrict__ mask,
                          const float* __restrict__ W, const float* __restrict__ b,
                          float* __restrict__ out) {
    int g = blockIdx.x, t = threadIdx.x;
    __shared__ float mloc[NPG];
    __shared__ float pooled[EMB];
    __shared__ float cnt;
    if (t < NPG) mloc[t] = mask[g * NPG + t];
    __syncthreads();
    if (t == 0) {
        float c = 0.f;
        for (int n = 0; n < NPG; ++n) c += mloc[n];
        cnt = fmaxf(c, 1.f);
    }
    __syncthreads();
    for (int c0 = t; c0 < EMB; c0 += 256) {
        float acc = 0.f;
        for (int n = 0; n < NPG; ++n)
            acc += mloc[n] * hc[((size_t)g * NPG + n) * EMBP + c0];
        pooled[c0] = acc / cnt;
    }
    __syncthreads();
    if (t < NOUT) {
        float acc = b[t];
        for (int c0 = 0; c0 < EMB; ++c0) acc += pooled[c0] * W[c0 * NOUT + t];
        out[g * NOUT + t] = acc;
    }
}

// ============================================================================
extern "C" void kernel_launch(void* const* d_in, const int* in_sizes, int n_in,
                              void* d_out, int out_size, void* d_ws, size_t ws_size,
                              hipStream_t stream) {
    const float* x        = (const float*)d_in[0];
    const int*   eidx     = (const int*)d_in[1];
    const float* enc_in_W = (const float*)d_in[4];
    const float* enc_in_b = (const float*)d_in[5];
    const float* enc_W1   = (const float*)d_in[6];
    const float* enc_b1   = (const float*)d_in[7];
    const float* enc_W2   = (const float*)d_in[8];
    const float* enc_b2   = (const float*)d_in[9];
    const float* enc_eps  = (const float*)d_in[10];
    const float* att_W1   = (const float*)d_in[11];
    const float* att_b1   = (const float*)d_in[12];
    const float* att_W2   = (const float*)d_in[13];
    const float* att_b2   = (const float*)d_in[14];
    const float* clf_in_W = (const float*)d_in[15];
    const float* clf_in_b = (const float*)d_in[16];
    const float* clf_W1   = (const float*)d_in[17];
    const float* clf_b1   = (const float*)d_in[18];
    const float* clf_W2   = (const float*)d_in[19];
    const float* clf_b2   = (const float*)d_in[20];
    const float* clf_eps  = (const float*)d_in[21];
    const float* pred_W   = (const float*)d_in[22];
    const float* pred_b   = (const float*)d_in[23];
    float* out = (float*)d_out;

    const int* src = eidx;
    const int* dst = eidx + N_EDGES;

    // ---------------- workspace layout (ws_size = 256 MiB per harness poison) ----
    char* ws = (char*)d_ws;
    constexpr size_t SZ_H    = (size_t)NPAD * EMBP * 4;        //  25,722,880
    constexpr size_t SZ_ZP   = (size_t)NPAD * EMBP * 2;        //  12,861,440 per plane
    constexpr size_t SZ_TP   = (size_t)NPAD * H2P * 2;         //  25,722,880 per plane (FULL)
    constexpr size_t SZ_WSP  = (size_t)H2P * EMBP * 2;         //     409,600 per plane
    constexpr size_t SZ_WUVP = (size_t)UVM * EMBP * 2;         //   1,556,480 per plane

    constexpr size_t OFF_H   = 0;
    constexpr size_t OFF_Z   = OFF_H + SZ_H;                   //  25,722,880
    constexpr size_t OFF_T   = OFF_Z + 3 * SZ_ZP;              //  64,307,200
    constexpr size_t OFF_WSL = OFF_T + 3 * SZ_TP;              // 141,475,840
    constexpr size_t OFF_AT  = OFF_WSL + 6 * SZ_WSP;           // 143,933,440
    constexpr size_t OFF_SC  = OFF_AT + (size_t)N_GRAPHS * NPG * NPG * 4;  // 151,933,440
    constexpr size_t OFF_CW  = OFF_SC + (size_t)N_EDGES * 4;
    constexpr size_t OFF_MK  = OFF_CW + (size_t)N_GRAPHS * TOPK * 4;
    constexpr size_t OFF_CS  = OFF_MK + (size_t)N_NODES * 4;
    constexpr size_t OFF_CD  = OFF_CS + (size_t)N_GRAPHS * TOPK * 4;
    constexpr size_t OFF_UV  = OFF_CD + (size_t)N_GRAPHS * TOPK * 4;       // 152,713,440
    // uvbuf = UVROWS x UVM x 4 = 98,369,536 -> high water 251,082,976 < 256 MiB

    float*  h   = (float*)(ws + OFF_H);
    ushort* z0  = (ushort*)(ws + OFF_Z);
    ushort* z1  = (ushort*)(ws + OFF_Z + SZ_ZP);
    ushort* z2  = (ushort*)(ws + OFF_Z + 2 * SZ_ZP);
    ushort* t0  = (ushort*)(ws + OFF_T);
    ushort* t1  = (ushort*)(ws + OFF_T + SZ_TP);
    ushort* t2  = (ushort*)(ws + OFF_T + 2 * SZ_TP);
    ushort* w0p[3] = {(ushort*)(ws + OFF_WSL), (ushort*)(ws + OFF_WSL + SZ_WSP),
                      (ushort*)(ws + OFF_WSL + 2 * SZ_WSP)};
    ushort* w1p[3] = {(ushort*)(ws + OFF_WSL + 3 * SZ_WSP), (ushort*)(ws + OFF_WSL + 4 * SZ_WSP),
                      (ushort*)(ws + OFF_WSL + 5 * SZ_WSP)};
    float*  At    = (float*)(ws + OFF_AT);
    float*  score = (float*)(ws + OFF_SC);
    float*  c_w   = (float*)(ws + OFF_CW);
    float*  mask  = (float*)(ws + OFF_MK);
    int*    c_src = (int*)(ws + OFF_CS);
    int*    c_dst = (int*)(ws + OFF_CD);
    float*  uvbuf = (float*)(ws + OFF_UV);

    // overlays
    ushort* xp[3] = {z0, z1, z2};              // x planes live in z region pre-layers
    // phase S: wuv planes live in the (dead) t region
    ushort* wuvp[3] = {(ushort*)(ws + OFF_T), (ushort*)(ws + OFF_T + SZ_WUVP),
                       (ushort*)(ws + OFF_T + 2 * SZ_WUVP)};

    // ================= Phase E: encoder (NT=3) =================
    conv_w<3><<<(EMBP * 64) / 256, 256, 0, stream>>>(enc_in_W, D_IN, EMB, 64, EMBP,
                                                     w0p[0], w0p[1], w0p[2]);
    conv_a<3><<<(int)(((long)NPAD * 64) / 256), 256, 0, stream>>>(
        x, N_NODES, D_IN, D_IN, 64, xp[0], xp[1], xp[2], (long)NPAD * 64);
    mfma_gemm<3, 0, 0, 64><<<dim3(EMBP / 64, NPAD / 128), 256, 0, stream>>>(
        xp[0], xp[1], xp[2], w0p[0], w0p[1], w0p[2], enc_in_b, 64, EMB, EMBP,
        h, nullptr, nullptr, nullptr);

    hipMemsetAsync(At, 0, (size_t)N_GRAPHS * NPG * NPG * 4, stream);
    build_At<<<cdiv(N_EDGES, 256), 256, 0, stream>>>(src, dst, nullptr, At, N_EDGES);

    for (int l = 0; l < NLAYERS; ++l) {
        agg_gemm<3><<<dim3(N_GRAPHS, 5), 256, 0, stream>>>(h, At, enc_eps, l, z0, z1, z2);
        conv_w2<3><<<(2 * H2P * EMBP) / 256, 256, 0, stream>>>(
            enc_W1 + (size_t)l * EMB * H2, enc_W2 + (size_t)l * H2 * EMB,
            w0p[0], w0p[1], w0p[2], w1p[0], w1p[1], w1p[2]);
        mfma_gemm<3, 1, 1, 128><<<dim3(H2P / 128, NPAD / 128), 256, 0, stream>>>(
            z0, z1, z2, w0p[0], w0p[1], w0p[2], enc_b1 + l * H2, EMBP, H2, H2P,
            nullptr, t0, t1, t2);
        if (l < NLAYERS - 1)
            mfma_gemm<3, 1, 0, 64><<<dim3(EMBP / 64, NPAD / 128), 256, 0, stream>>>(
                t0, t1, t2, w1p[0], w1p[1], w1p[2], enc_b2 + l * EMB, H2P, EMB, EMBP,
                h, nullptr, nullptr, nullptr);
        else   // final layer: emit bf16 planes (no relu) straight into z region
            mfma_gemm<3, 0, 1, 64><<<dim3(EMBP / 64, NPAD / 128), 256, 0, stream>>>(
                t0, t1, t2, w1p[0], w1p[1], w1p[2], enc_b2 + l * EMB, H2P, EMB, EMBP,
                nullptr, z0, z1, z2);
    }

    // ================= Phase S: edge scores + topk (2 chunks) =================
    // stacked Wu|Wv planes (bias folded into edge_score)
    conv_w<3><<<cdiv(1216 * EMBP, 256), 256, 0, stream>>>(
        att_W1, EMB, H4, EMBP, 1216, wuvp[0], wuvp[1], wuvp[2]);
    conv_w<3><<<cdiv(1216 * EMBP, 256), 256, 0, stream>>>(
        att_W1 + (size_t)EMB * H4, EMB, H4, EMBP, 1216,
        wuvp[0] + (size_t)1216 * EMBP, wuvp[1] + (size_t)1216 * EMBP,
        wuvp[2] + (size_t)1216 * EMBP);
    for (int sc = 0; sc < 2; ++sc) {
        size_t nb0 = (size_t)sc * 10000;           // node base (0 / 10000)
        // rows nb0..nb0+10112 cover all nodes of this chunk's graphs; the few
        // OOB rows past NPAD read mapped ws (finite bf16) and feed unused uv rows.
        mfma_gemm<3, 0, 0, 128><<<dim3(UVM / 128, UVROWS / 128), 256, 0, stream>>>(
            z0 + nb0 * EMBP, z1 + nb0 * EMBP, z2 + nb0 * EMBP,
            wuvp[0], wuvp[1], wuvp[2], nullptr, EMBP, UVM, UVM,
            uvbuf, nullptr, nullptr, nullptr);
        edge_score<<<cdiv(N_EDGES / 2, 4), 256, 0, stream>>>(
            uvbuf, att_b1, att_W2, att_b2, src + sc * 50000, dst + sc * 50000,
            score + sc * 50000, N_EDGES / 2, (int)nb0);
    }
    hipMemsetAsync(mask, 0, N_NODES * 4, stream);
    topk_kernel<<<N_GRAPHS, 512, 0, stream>>>(score, src, dst, c_src, c_dst, c_w, mask);

    // ================= Phase C: classifier (NT=2) =================
    conv_w<2><<<(EMBP * 64) / 256, 256, 0, stream>>>(clf_in_W, D_IN, EMB, 64, EMBP,
                                                     w0p[0], w0p[1], w0p[2]);
    conv_a<2><<<(int)(((long)NPAD * 64) / 256), 256, 0, stream>>>(
        x, N_NODES, D_IN, D_IN, 64, xp[0], xp[1], nullptr, (long)NPAD * 64);
    mfma_gemm<2, 0, 0, 64><<<dim3(EMBP / 64, NPAD / 128), 256, 0, stream>>>(
        xp[0], xp[1], nullptr, w0p[0], w0p[1], nullptr, clf_in_b, 64, EMB, EMBP,
        h, nullptr, nullptr, nullptr);

    hipMemsetAsync(At, 0, (size_t)N_GRAPHS * NPG * NPG * 4, stream);
    build_At<<<cdiv(N_GRAPHS * TOPK, 256), 256, 0, stream>>>(c_src, c_dst, c_w, At,
                                                             N_GRAPHS * TOPK);

    for (int l = 0; l < NLAYERS; ++l) {
        agg_gemm<2><<<dim3(N_GRAPHS, 5), 256, 0, stream>>>(h, At, clf_eps, l,
                                                           z0, z1, nullptr);
        conv_w2<2><<<(2 * H2P * EMBP) / 256, 256, 0, stream>>>(
            clf_W1 + (size_t)l * EMB * H2, clf_W2 + (size_t)l * H2 * EMB,
            w0p[0], w0p[1], nullptr, w1p[0], w1p[1], nullptr);
        mfma_gemm<2, 1, 1, 128><<<dim3(H2P / 128, NPAD / 128), 256, 0, stream>>>(
            z0, z1, nullptr, w0p[0], w0p[1], nullptr, clf_b1 + l * H2, EMBP, H2, H2P,
            nullptr, t0, t1, nullptr);
        if (l < NLAYERS - 1)
            mfma_gemm<2, 1, 0, 64><<<dim3(EMBP / 64, NPAD / 128), 256, 0, stream>>>(
                t0, t1, nullptr, w1p[0], w1p[1], nullptr, clf_b2 + l * EMB, H2P, EMB, EMBP,
                h, nullptr, nullptr, nullptr);
        else
            mfma_gemm<2, 0, 0, 64><<<dim3(EMBP / 64, NPAD / 128), 256, 0, stream>>>(
                t0, t1, nullptr, w1p[0], w1p[1], nullptr, clf_b2 + l * EMB, H2P, EMB, EMBP,
                h, nullptr, nullptr, nullptr);
    }

    // ================= pool + head =================
    pool_pred<<<N_GRAPHS, 256, 0, stream>>>(h, mask, pred_W, pred_b, out);
}